// Round 1
// baseline (6375.258 us; speedup 1.0000x reference)
//
#include <hip/hip_runtime.h>

#define N_NODES 50000
#define E_EDGES 400000
#define DIM     512
#define NRSU    1000

// ---------------- degree / normalization ----------------
__global__ void k_deg_init(float* __restrict__ deg) {
    int i = blockIdx.x * 256 + threadIdx.x;
    if (i < N_NODES) deg[i] = 1.0f;   // self-loop
}

__global__ void k_deg_edges(const int* __restrict__ dst, float* __restrict__ deg) {
    int e = blockIdx.x * 256 + threadIdx.x;
    if (e < E_EDGES) atomicAdd(&deg[dst[e]], 1.0f);
}

__global__ void k_deg_fin(float* __restrict__ deg) {
    int i = blockIdx.x * 256 + threadIdx.x;
    if (i < N_NODES) deg[i] = rsqrtf(deg[i]);   // deg >= 1 always (self-loop)
}

// ---------------- fp32 tiled GEMM: C[M x 512] = act(A)[M x 512] @ B[512 x 512] ----------------
template<bool RELU>
__global__ __launch_bounds__(256) void k_gemm(const float* __restrict__ A,
                                              const float* __restrict__ B,
                                              float* __restrict__ C, int M) {
    const int BM = 128, BN = 64, BK = 16;
    __shared__ float As[BK][BM + 4];
    __shared__ float Bs[BK][BN + 4];
    int row0 = blockIdx.x * BM;
    int col0 = blockIdx.y * BN;
    int tid = threadIdx.x;
    int ty = tid >> 4;      // 0..15 -> rows ty*8..+8
    int tx = tid & 15;      // 0..15 -> cols tx*4..+4
    float acc[8][4] = {};

    for (int k0 = 0; k0 < DIM; k0 += BK) {
        // A tile: 128x16 = 512 float4, 2 per thread; store transposed As[k][row]
        #pragma unroll
        for (int l = 0; l < 2; ++l) {
            int f = tid + l * 256;          // 0..511
            int r = f >> 2;                 // 0..127
            int kb = (f & 3) * 4;           // 0,4,8,12
            int grow = row0 + r;
            float4 v = make_float4(0.f, 0.f, 0.f, 0.f);
            if (grow < M)
                v = *reinterpret_cast<const float4*>(A + (size_t)grow * DIM + k0 + kb);
            if (RELU) {
                v.x = fmaxf(v.x, 0.f); v.y = fmaxf(v.y, 0.f);
                v.z = fmaxf(v.z, 0.f); v.w = fmaxf(v.w, 0.f);
            }
            As[kb + 0][r] = v.x; As[kb + 1][r] = v.y;
            As[kb + 2][r] = v.z; As[kb + 3][r] = v.w;
        }
        // B tile: 16x64 = 256 float4, 1 per thread
        {
            int r = tid >> 4;               // k 0..15
            int c = (tid & 15) * 4;         // 0..60
            float4 v = *reinterpret_cast<const float4*>(B + (size_t)(k0 + r) * DIM + col0 + c);
            *reinterpret_cast<float4*>(&Bs[r][c]) = v;
        }
        __syncthreads();
        #pragma unroll
        for (int k = 0; k < BK; ++k) {
            float a[8], b[4];
            #pragma unroll
            for (int i = 0; i < 8; ++i) a[i] = As[k][ty * 8 + i];
            #pragma unroll
            for (int j = 0; j < 4; ++j) b[j] = Bs[k][tx * 4 + j];
            #pragma unroll
            for (int i = 0; i < 8; ++i)
                #pragma unroll
                for (int j = 0; j < 4; ++j)
                    acc[i][j] = fmaf(a[i], b[j], acc[i][j]);
        }
        __syncthreads();
    }
    #pragma unroll
    for (int i = 0; i < 8; ++i) {
        int grow = row0 + ty * 8 + i;
        if (grow < M) {
            float4 v = make_float4(acc[i][0], acc[i][1], acc[i][2], acc[i][3]);
            *reinterpret_cast<float4*>(C + (size_t)grow * DIM + col0 + tx * 4) = v;
        }
    }
}

// ---------------- aggregation init: agg[i][:] = bias + dinv[i]^2 * pre[i][:] (self-loop) --------
__global__ void k_init_agg(const float* __restrict__ pre, const float* __restrict__ bias,
                           const float* __restrict__ dinv, float* __restrict__ agg) {
    size_t idx = ((size_t)blockIdx.x * 256 + threadIdx.x) * 4;
    if (idx >= (size_t)N_NODES * DIM) return;
    int row = (int)(idx >> 9);
    int col = (int)(idx & 511);
    float di = dinv[row];
    float w = di * di;
    float4 p = *reinterpret_cast<const float4*>(pre + idx);
    float4 b = *reinterpret_cast<const float4*>(bias + col);
    float4 o;
    o.x = fmaf(w, p.x, b.x); o.y = fmaf(w, p.y, b.y);
    o.z = fmaf(w, p.z, b.z); o.w = fmaf(w, p.w, b.w);
    *reinterpret_cast<float4*>(agg + idx) = o;
}

// ---------------- edge scatter: agg[dst] += norm * pre[src], one wave per edge -----------------
__global__ __launch_bounds__(256) void k_agg_edges(const int* __restrict__ ei,
                                                   const float* __restrict__ dinv,
                                                   const float* __restrict__ pre,
                                                   float* __restrict__ agg) {
    int e = blockIdx.x * 4 + (threadIdx.x >> 6);
    if (e >= E_EDGES) return;
    int lane = threadIdx.x & 63;
    int s = ei[e];
    int d = ei[E_EDGES + e];
    float w = dinv[s] * dinv[d];
    const float* ps = pre + (size_t)s * DIM;
    float* pd = agg + (size_t)d * DIM;
    int c0 = lane * 4, c1 = 256 + lane * 4;
    float4 v0 = *reinterpret_cast<const float4*>(ps + c0);
    float4 v1 = *reinterpret_cast<const float4*>(ps + c1);
    atomicAdd(pd + c0 + 0, w * v0.x);
    atomicAdd(pd + c0 + 1, w * v0.y);
    atomicAdd(pd + c0 + 2, w * v0.z);
    atomicAdd(pd + c0 + 3, w * v0.w);
    atomicAdd(pd + c1 + 0, w * v1.x);
    atomicAdd(pd + c1 + 1, w * v1.y);
    atomicAdd(pd + c1 + 2, w * v1.z);
    atomicAdd(pd + c1 + 3, w * v1.w);
}

// ---------------- pooling ----------------
__global__ void k_pool_init(float* __restrict__ psum, int* __restrict__ pcnt) {
    int i = blockIdx.x * 256 + threadIdx.x;
    if (i < NRSU * DIM) psum[i] = 0.f;
    if (i < NRSU) pcnt[i] = 0;
}

__global__ __launch_bounds__(256) void k_pool_acc(const int* __restrict__ batch,
                                                  const float* __restrict__ h,
                                                  float* __restrict__ psum,
                                                  int* __restrict__ pcnt) {
    int node = NRSU + blockIdx.x * 4 + (threadIdx.x >> 6);
    if (node >= N_NODES) return;
    int lane = threadIdx.x & 63;
    int s = batch[node];
    if (lane == 0) atomicAdd(&pcnt[s], 1);
    const float* ph = h + (size_t)node * DIM;
    float* pp = psum + (size_t)s * DIM;
    int c0 = lane * 4, c1 = 256 + lane * 4;
    float4 v0 = *reinterpret_cast<const float4*>(ph + c0);
    float4 v1 = *reinterpret_cast<const float4*>(ph + c1);
    atomicAdd(pp + c0 + 0, v0.x);
    atomicAdd(pp + c0 + 1, v0.y);
    atomicAdd(pp + c0 + 2, v0.z);
    atomicAdd(pp + c0 + 3, v0.w);
    atomicAdd(pp + c1 + 0, v1.x);
    atomicAdd(pp + c1 + 1, v1.y);
    atomicAdd(pp + c1 + 2, v1.z);
    atomicAdd(pp + c1 + 3, v1.w);
}

// ---------------- final: out[i] = [h[i] , psum[i]/max(cnt,1)] ----------------
__global__ void k_final(const float* __restrict__ h, const float* __restrict__ psum,
                        const int* __restrict__ pcnt, float* __restrict__ out) {
    int i = blockIdx.x;          // 0..999
    int t = threadIdx.x;         // 0..255, 4 floats each
    float* orow = out + (size_t)i * 1024;
    if (t < 128) {
        float4 v = *reinterpret_cast<const float4*>(h + (size_t)i * DIM + t * 4);
        *reinterpret_cast<float4*>(orow + t * 4) = v;
    } else {
        float inv = 1.0f / fmaxf((float)pcnt[i], 1.0f);
        int c = (t - 128) * 4;
        float4 v = *reinterpret_cast<const float4*>(psum + (size_t)i * DIM + c);
        v.x *= inv; v.y *= inv; v.z *= inv; v.w *= inv;
        *reinterpret_cast<float4*>(orow + 512 + c) = v;
    }
}

extern "C" void kernel_launch(void* const* d_in, const int* in_sizes, int n_in,
                              void* d_out, int out_size, void* d_ws, size_t ws_size,
                              hipStream_t stream) {
    const float* x     = (const float*)d_in[0];
    const int*   ei    = (const int*)d_in[1];   // [2][E] row-major
    const int*   batch = (const int*)d_in[2];
    const float* W1    = (const float*)d_in[3];
    const float* b1    = (const float*)d_in[4];
    const float* W2    = (const float*)d_in[5];
    const float* b2    = (const float*)d_in[6];
    float* out = (float*)d_out;

    char* ws = (char*)d_ws;
    const size_t FEAT_BYTES = (size_t)N_NODES * DIM * sizeof(float);   // 102,400,000
    float* bufA = (float*)(ws);                         // pre-activations
    float* bufB = (float*)(ws + FEAT_BYTES);            // aggregated
    float* dinv = (float*)(ws + 2 * FEAT_BYTES);        // degree -> rsqrt(deg)
    float* psum = (float*)(ws + 2 * FEAT_BYTES + (size_t)256 * 1024);  // pooled sums (offset padded)
    int*   pcnt = (int*)  (ws + 2 * FEAT_BYTES + (size_t)256 * 1024 + (size_t)NRSU * DIM * sizeof(float));

    dim3 blk(256);
    // degree + rsqrt
    k_deg_init <<<(N_NODES + 255) / 256, blk, 0, stream>>>(dinv);
    k_deg_edges<<<(E_EDGES + 255) / 256, blk, 0, stream>>>(ei + E_EDGES, dinv);
    k_deg_fin  <<<(N_NODES + 255) / 256, blk, 0, stream>>>(dinv);

    dim3 ggrid((N_NODES + 127) / 128, DIM / 64);
    const int agg_grid  = (E_EDGES + 3) / 4;
    const int init_grid = (int)(((size_t)N_NODES * DIM / 4 + 255) / 256);

    // layer 1
    k_gemm<false><<<ggrid, blk, 0, stream>>>(x, W1, bufA, N_NODES);
    k_init_agg  <<<init_grid, blk, 0, stream>>>(bufA, b1, dinv, bufB);
    k_agg_edges <<<agg_grid, blk, 0, stream>>>(ei, dinv, bufA, bufB);

    // layer 2 (ReLU fused into A-load)
    k_gemm<true><<<ggrid, blk, 0, stream>>>(bufB, W2, bufA, N_NODES);
    k_init_agg  <<<init_grid, blk, 0, stream>>>(bufA, b2, dinv, bufB);
    k_agg_edges <<<agg_grid, blk, 0, stream>>>(ei, dinv, bufA, bufB);

    // pooling + output
    k_pool_init<<<(NRSU * DIM + 255) / 256, blk, 0, stream>>>(psum, pcnt);
    k_pool_acc <<<((N_NODES - NRSU) + 3) / 4, blk, 0, stream>>>(batch, bufB, psum, pcnt);
    k_final    <<<NRSU, blk, 0, stream>>>(bufB, psum, pcnt, out);
}

// Round 2
// 1019.974 us; speedup vs baseline: 6.2504x; 6.2504x over previous
//
#include <hip/hip_runtime.h>

#define N_NODES 50000
#define E_EDGES 400000
#define DIM     512
#define NRSU    1000
#define NB_SCAN 196           // ceil(50000/256)

// ---------------- zero int array ----------------
__global__ void k_zero_int(int* __restrict__ p, int n) {
    int i = blockIdx.x * 256 + threadIdx.x;
    if (i < n) p[i] = 0;
}

// ---------------- in-degree count (edges only; self-loop added later) ----------------
__global__ void k_count(const int* __restrict__ dst, int* __restrict__ cnt) {
    int e = blockIdx.x * 256 + threadIdx.x;
    if (e < E_EDGES) atomicAdd(&cnt[dst[e]], 1);
}

// ---------------- block-wise exclusive scan (Hillis-Steele) ----------------
__global__ __launch_bounds__(256) void k_scan1(const int* __restrict__ cnt,
                                               int* __restrict__ rowptr,
                                               int* __restrict__ bsum) {
    __shared__ int sh[256];
    int tid = threadIdx.x;
    int i = blockIdx.x * 256 + tid;
    int v = (i < N_NODES) ? cnt[i] : 0;
    sh[tid] = v;
    __syncthreads();
    #pragma unroll
    for (int off = 1; off < 256; off <<= 1) {
        int t = (tid >= off) ? sh[tid - off] : 0;
        __syncthreads();
        sh[tid] += t;
        __syncthreads();
    }
    if (i < N_NODES) rowptr[i] = sh[tid] - v;           // exclusive within block
    if (tid == 255) bsum[blockIdx.x] = sh[255];
}

__global__ __launch_bounds__(256) void k_scan2(int* __restrict__ bsum) {
    __shared__ int sh[256];
    int tid = threadIdx.x;
    int v = (tid < NB_SCAN) ? bsum[tid] : 0;
    sh[tid] = v;
    __syncthreads();
    #pragma unroll
    for (int off = 1; off < 256; off <<= 1) {
        int t = (tid >= off) ? sh[tid - off] : 0;
        __syncthreads();
        sh[tid] += t;
        __syncthreads();
    }
    if (tid < NB_SCAN) bsum[tid] = sh[tid] - v;         // exclusive block offsets
}

__global__ void k_scan3(int* __restrict__ rowptr, const int* __restrict__ bsum) {
    int i = blockIdx.x * 256 + threadIdx.x;
    if (i < N_NODES) rowptr[i] += bsum[blockIdx.x];
    if (i == 0) rowptr[N_NODES] = E_EDGES;
}

// ---------------- dinv = rsqrt(in_deg + 1)  (self-loop) ----------------
__global__ void k_deg_fin(const int* __restrict__ cnt, float* __restrict__ dinv) {
    int i = blockIdx.x * 256 + threadIdx.x;
    if (i < N_NODES) dinv[i] = rsqrtf((float)cnt[i] + 1.0f);
}

// ---------------- CSR fill: col grouped by dst ----------------
__global__ void k_fill(const int* __restrict__ ei, const int* __restrict__ rowptr,
                       int* __restrict__ fill, int* __restrict__ col) {
    int e = blockIdx.x * 256 + threadIdx.x;
    if (e >= E_EDGES) return;
    int s = ei[e];
    int d = ei[E_EDGES + e];
    int p = atomicAdd(&fill[d], 1);
    col[rowptr[d] + p] = s;
}

// ---------------- segment boundaries for pooling (batch monotone over vehicles) ----
__global__ void k_segbounds(const int* __restrict__ batch, int* __restrict__ seg) {
    const int n_veh = N_NODES - NRSU;
    int v = blockIdx.x * 256 + threadIdx.x;
    if (v >= n_veh) return;
    int b = batch[NRSU + v];
    if (v == 0) {
        for (int s = 0; s <= b; ++s) seg[s] = 0;
    } else {
        int bp = batch[NRSU + v - 1];
        for (int s = bp + 1; s <= b; ++s) seg[s] = v;
    }
    if (v == n_veh - 1) {
        for (int s = b + 1; s <= NRSU; ++s) seg[s] = n_veh;
    }
}

// ---------------- fp32 tiled GEMM: C[M x 512] = act(A)[M x 512] @ B[512 x 512] ----------------
template<bool RELU>
__global__ __launch_bounds__(256) void k_gemm(const float* __restrict__ A,
                                              const float* __restrict__ B,
                                              float* __restrict__ C, int M) {
    const int BM = 128, BN = 64, BK = 16;
    __shared__ float As[BK][BM + 4];
    __shared__ float Bs[BK][BN + 4];
    int row0 = blockIdx.x * BM;
    int col0 = blockIdx.y * BN;
    int tid = threadIdx.x;
    int ty = tid >> 4;
    int tx = tid & 15;
    float acc[8][4] = {};

    for (int k0 = 0; k0 < DIM; k0 += BK) {
        #pragma unroll
        for (int l = 0; l < 2; ++l) {
            int f = tid + l * 256;
            int r = f >> 2;
            int kb = (f & 3) * 4;
            int grow = row0 + r;
            float4 v = make_float4(0.f, 0.f, 0.f, 0.f);
            if (grow < M)
                v = *reinterpret_cast<const float4*>(A + (size_t)grow * DIM + k0 + kb);
            if (RELU) {
                v.x = fmaxf(v.x, 0.f); v.y = fmaxf(v.y, 0.f);
                v.z = fmaxf(v.z, 0.f); v.w = fmaxf(v.w, 0.f);
            }
            As[kb + 0][r] = v.x; As[kb + 1][r] = v.y;
            As[kb + 2][r] = v.z; As[kb + 3][r] = v.w;
        }
        {
            int r = tid >> 4;
            int c = (tid & 15) * 4;
            float4 v = *reinterpret_cast<const float4*>(B + (size_t)(k0 + r) * DIM + col0 + c);
            *reinterpret_cast<float4*>(&Bs[r][c]) = v;
        }
        __syncthreads();
        #pragma unroll
        for (int k = 0; k < BK; ++k) {
            float a[8], b[4];
            #pragma unroll
            for (int i = 0; i < 8; ++i) a[i] = As[k][ty * 8 + i];
            #pragma unroll
            for (int j = 0; j < 4; ++j) b[j] = Bs[k][tx * 4 + j];
            #pragma unroll
            for (int i = 0; i < 8; ++i)
                #pragma unroll
                for (int j = 0; j < 4; ++j)
                    acc[i][j] = fmaf(a[i], b[j], acc[i][j]);
        }
        __syncthreads();
    }
    #pragma unroll
    for (int i = 0; i < 8; ++i) {
        int grow = row0 + ty * 8 + i;
        if (grow < M) {
            float4 v = make_float4(acc[i][0], acc[i][1], acc[i][2], acc[i][3]);
            *reinterpret_cast<float4*>(C + (size_t)grow * DIM + col0 + tx * 4) = v;
        }
    }
}

// ---------------- CSR gather aggregation: agg[i] = b + dinv[i]^2*pre[i] + sum_j w*pre[src_j]
__global__ __launch_bounds__(256) void k_gather(const int* __restrict__ rowptr,
                                                const int* __restrict__ col,
                                                const float* __restrict__ dinv,
                                                const float* __restrict__ pre,
                                                const float* __restrict__ bias,
                                                float* __restrict__ agg) {
    int node = blockIdx.x * 4 + (threadIdx.x >> 6);
    if (node >= N_NODES) return;
    int lane = threadIdx.x & 63;
    int c0 = lane * 4, c1 = 256 + lane * 4;

    float di = dinv[node];
    float w0 = di * di;
    const float* prow = pre + (size_t)node * DIM;
    float4 a0 = *reinterpret_cast<const float4*>(prow + c0);
    float4 a1 = *reinterpret_cast<const float4*>(prow + c1);
    float4 bb0 = *reinterpret_cast<const float4*>(bias + c0);
    float4 bb1 = *reinterpret_cast<const float4*>(bias + c1);
    float4 s0, s1;
    s0.x = fmaf(w0, a0.x, bb0.x); s0.y = fmaf(w0, a0.y, bb0.y);
    s0.z = fmaf(w0, a0.z, bb0.z); s0.w = fmaf(w0, a0.w, bb0.w);
    s1.x = fmaf(w0, a1.x, bb1.x); s1.y = fmaf(w0, a1.y, bb1.y);
    s1.z = fmaf(w0, a1.z, bb1.z); s1.w = fmaf(w0, a1.w, bb1.w);

    int beg = rowptr[node], end = rowptr[node + 1];
    for (int j = beg; j < end; ++j) {
        int src = col[j];
        float w = dinv[src] * di;
        const float* sr = pre + (size_t)src * DIM;
        float4 v0 = *reinterpret_cast<const float4*>(sr + c0);
        float4 v1 = *reinterpret_cast<const float4*>(sr + c1);
        s0.x = fmaf(w, v0.x, s0.x); s0.y = fmaf(w, v0.y, s0.y);
        s0.z = fmaf(w, v0.z, s0.z); s0.w = fmaf(w, v0.w, s0.w);
        s1.x = fmaf(w, v1.x, s1.x); s1.y = fmaf(w, v1.y, s1.y);
        s1.z = fmaf(w, v1.z, s1.z); s1.w = fmaf(w, v1.w, s1.w);
    }
    float* orow = agg + (size_t)node * DIM;
    *reinterpret_cast<float4*>(orow + c0) = s0;
    *reinterpret_cast<float4*>(orow + c1) = s1;
}

// ---------------- fused pool + output: out[s] = [h[s], mean(veh rows of seg s)] -----
__global__ __launch_bounds__(128) void k_pool_out(const float* __restrict__ h,
                                                  const int* __restrict__ seg,
                                                  float* __restrict__ out) {
    int s = blockIdx.x;            // 0..999
    int c = threadIdx.x * 4;       // 0..508
    float* orow = out + (size_t)s * 1024;
    float4 r = *reinterpret_cast<const float4*>(h + (size_t)s * DIM + c);
    *reinterpret_cast<float4*>(orow + c) = r;

    int beg = seg[s], end = seg[s + 1];
    float4 acc = make_float4(0.f, 0.f, 0.f, 0.f);
    for (int v = beg; v < end; ++v) {
        float4 t = *reinterpret_cast<const float4*>(h + (size_t)(NRSU + v) * DIM + c);
        acc.x += t.x; acc.y += t.y; acc.z += t.z; acc.w += t.w;
    }
    float inv = 1.0f / fmaxf((float)(end - beg), 1.0f);
    acc.x *= inv; acc.y *= inv; acc.z *= inv; acc.w *= inv;
    *reinterpret_cast<float4*>(orow + 512 + c) = acc;
}

extern "C" void kernel_launch(void* const* d_in, const int* in_sizes, int n_in,
                              void* d_out, int out_size, void* d_ws, size_t ws_size,
                              hipStream_t stream) {
    const float* x     = (const float*)d_in[0];
    const int*   ei    = (const int*)d_in[1];   // [2][E] row-major
    const int*   batch = (const int*)d_in[2];
    const float* W1    = (const float*)d_in[3];
    const float* b1    = (const float*)d_in[4];
    const float* W2    = (const float*)d_in[5];
    const float* b2    = (const float*)d_in[6];
    float* out = (float*)d_out;

    char* ws = (char*)d_ws;
    const size_t FEAT_BYTES = (size_t)N_NODES * DIM * sizeof(float);   // 102,400,000
    float* bufA   = (float*)(ws);
    float* bufB   = (float*)(ws + FEAT_BYTES);
    char*  p      = ws + 2 * FEAT_BYTES;
    float* dinv   = (float*)p;                 p += (size_t)N_NODES * 4;
    int*   cnt    = (int*)p;                   p += (size_t)N_NODES * 4;   // reused as fill
    int*   rowptr = (int*)p;                   p += (size_t)(N_NODES + 4) * 4;
    int*   col    = (int*)p;                   p += (size_t)E_EDGES * 4;
    int*   bsum   = (int*)p;                   p += 1024;
    int*   seg    = (int*)p;                   p += (size_t)(NRSU + 4) * 4;

    dim3 blk(256);
    const int gN = (N_NODES + 255) / 256;      // 196
    const int gE = (E_EDGES + 255) / 256;

    // ---- CSR build + norm ----
    k_zero_int <<<gN, blk, 0, stream>>>(cnt, N_NODES);
    k_count    <<<gE, blk, 0, stream>>>(ei + E_EDGES, cnt);
    k_scan1    <<<gN, blk, 0, stream>>>(cnt, rowptr, bsum);
    k_scan2    <<<1,  blk, 0, stream>>>(bsum);
    k_scan3    <<<gN, blk, 0, stream>>>(rowptr, bsum);
    k_deg_fin  <<<gN, blk, 0, stream>>>(cnt, dinv);
    k_zero_int <<<gN, blk, 0, stream>>>(cnt, N_NODES);          // reuse as fill counters
    k_fill     <<<gE, blk, 0, stream>>>(ei, rowptr, cnt, col);
    k_segbounds<<<((N_NODES - NRSU) + 255) / 256, blk, 0, stream>>>(batch, seg);

    // ---- layer 1 ----
    dim3 ggrid((N_NODES + 127) / 128, DIM / 64);
    k_gemm<false><<<ggrid, blk, 0, stream>>>(x, W1, bufA, N_NODES);
    k_gather     <<<(N_NODES + 3) / 4, blk, 0, stream>>>(rowptr, col, dinv, bufA, b1, bufB);

    // ---- layer 2 (ReLU fused into GEMM A-load) ----
    k_gemm<true> <<<ggrid, blk, 0, stream>>>(bufB, W2, bufA, N_NODES);
    k_gather     <<<(N_NODES + 3) / 4, blk, 0, stream>>>(rowptr, col, dinv, bufA, b2, bufB);

    // ---- pool + output ----
    k_pool_out   <<<NRSU, dim3(128), 0, stream>>>(bufB, seg, out);
}

// Round 3
// 613.996 us; speedup vs baseline: 10.3832x; 1.6612x over previous
//
#include <hip/hip_runtime.h>

#define N_NODES 50000
#define E_EDGES 400000
#define DIM     512
#define NRSU    1000
#define NB_SCAN 196           // ceil(50000/256)

typedef __attribute__((ext_vector_type(8))) __bf16 bf16x8;
typedef __attribute__((ext_vector_type(4))) float  f32x4;

struct __align__(8) ush4 { unsigned short x, y, z, w; };

// ---------- bf16 split helpers (RNE) ----------
__device__ __forceinline__ unsigned short f2bf_rne(float x) {
    unsigned u = __float_as_uint(x);
    unsigned r = u + 0x7fff + ((u >> 16) & 1);
    return (unsigned short)(r >> 16);
}
__device__ __forceinline__ float bf2f(unsigned short b) {
    return __uint_as_float((unsigned)b << 16);
}
__device__ __forceinline__ void split1(float v, unsigned short& h, unsigned short& l) {
    h = f2bf_rne(v);
    l = f2bf_rne(v - bf2f(h));
}

// ---------- async global->LDS (16B per lane) ----------
typedef __attribute__((address_space(1))) const unsigned char ga_u8;
typedef __attribute__((address_space(3))) unsigned char la_u8;
__device__ __forceinline__ void gload16(const void* g, void* l) {
    __builtin_amdgcn_global_load_lds((ga_u8*)g, (la_u8*)l, 16, 0, 0);
}

// ---------------- zero int array ----------------
__global__ void k_zero_int(int* __restrict__ p, int n) {
    int i = blockIdx.x * 256 + threadIdx.x;
    if (i < n) p[i] = 0;
}

// ---------------- in-degree count ----------------
__global__ void k_count(const int* __restrict__ dst, int* __restrict__ cnt) {
    int e = blockIdx.x * 256 + threadIdx.x;
    if (e < E_EDGES) atomicAdd(&cnt[dst[e]], 1);
}

// ---------------- block-wise exclusive scan ----------------
__global__ __launch_bounds__(256) void k_scan1(const int* __restrict__ cnt,
                                               int* __restrict__ rowptr,
                                               int* __restrict__ bsum) {
    __shared__ int sh[256];
    int tid = threadIdx.x;
    int i = blockIdx.x * 256 + tid;
    int v = (i < N_NODES) ? cnt[i] : 0;
    sh[tid] = v;
    __syncthreads();
    #pragma unroll
    for (int off = 1; off < 256; off <<= 1) {
        int t = (tid >= off) ? sh[tid - off] : 0;
        __syncthreads();
        sh[tid] += t;
        __syncthreads();
    }
    if (i < N_NODES) rowptr[i] = sh[tid] - v;
    if (tid == 255) bsum[blockIdx.x] = sh[255];
}

__global__ __launch_bounds__(256) void k_scan2(int* __restrict__ bsum) {
    __shared__ int sh[256];
    int tid = threadIdx.x;
    int v = (tid < NB_SCAN) ? bsum[tid] : 0;
    sh[tid] = v;
    __syncthreads();
    #pragma unroll
    for (int off = 1; off < 256; off <<= 1) {
        int t = (tid >= off) ? sh[tid - off] : 0;
        __syncthreads();
        sh[tid] += t;
        __syncthreads();
    }
    if (tid < NB_SCAN) bsum[tid] = sh[tid] - v;
}

__global__ void k_scan3(int* __restrict__ rowptr, const int* __restrict__ bsum) {
    int i = blockIdx.x * 256 + threadIdx.x;
    if (i < N_NODES) rowptr[i] += bsum[blockIdx.x];
    if (i == 0) rowptr[N_NODES] = E_EDGES;
}

// ---------------- dinv = rsqrt(in_deg + 1) ----------------
__global__ void k_deg_fin(const int* __restrict__ cnt, float* __restrict__ dinv) {
    int i = blockIdx.x * 256 + threadIdx.x;
    if (i < N_NODES) dinv[i] = rsqrtf((float)cnt[i] + 1.0f);
}

// ---------------- CSR fill ----------------
__global__ void k_fill(const int* __restrict__ ei, const int* __restrict__ rowptr,
                       int* __restrict__ fill, int* __restrict__ col) {
    int e = blockIdx.x * 256 + threadIdx.x;
    if (e >= E_EDGES) return;
    int s = ei[e];
    int d = ei[E_EDGES + e];
    int p = atomicAdd(&fill[d], 1);
    col[rowptr[d] + p] = s;
}

// ---------------- segment boundaries (batch monotone over vehicles) ----
__global__ void k_segbounds(const int* __restrict__ batch, int* __restrict__ seg) {
    const int n_veh = N_NODES - NRSU;
    int v = blockIdx.x * 256 + threadIdx.x;
    if (v >= n_veh) return;
    int b = batch[NRSU + v];
    if (v == 0) {
        for (int s = 0; s <= b; ++s) seg[s] = 0;
    } else {
        int bp = batch[NRSU + v - 1];
        for (int s = bp + 1; s <= b; ++s) seg[s] = v;
    }
    if (v == n_veh - 1) {
        for (int s = b + 1; s <= NRSU; ++s) seg[s] = n_veh;
    }
}

// ---------------- W [K][N] -> W^T split bf16 hi/lo [N][K] ----------------
__global__ void k_wsplit(const float* __restrict__ W,
                         unsigned short* __restrict__ WhT,
                         unsigned short* __restrict__ WlT) {
    int n = blockIdx.x;
    for (int k = threadIdx.x; k < DIM; k += 256) {
        float v = W[(size_t)k * DIM + n];
        unsigned short h, l;
        split1(v, h, l);
        WhT[(size_t)n * DIM + k] = h;
        WlT[(size_t)n * DIM + k] = l;
    }
}

// ---------------- x -> bf16 hi/lo split ----------------
__global__ void k_split(const float* __restrict__ in,
                        unsigned short* __restrict__ hi,
                        unsigned short* __restrict__ lo) {
    size_t i = ((size_t)blockIdx.x * 256 + threadIdx.x) * 4;
    float4 v = *reinterpret_cast<const float4*>(in + i);
    ush4 h, l;
    split1(v.x, h.x, l.x);
    split1(v.y, h.y, l.y);
    split1(v.z, h.z, l.z);
    split1(v.w, h.w, l.w);
    *reinterpret_cast<ush4*>(hi + i) = h;
    *reinterpret_cast<ush4*>(lo + i) = l;
}

// ---------------- split-bf16 MFMA GEMM: C[M x 512] = (Ah+Al) @ (Bh+Bl) ----------------
// A: [M][512] bf16 hi/lo row-major; B^T: [512][512] bf16 hi/lo (n-major, k contiguous)
__global__ __launch_bounds__(256) void k_gemm_mfma(const unsigned short* __restrict__ Ah,
                                                   const unsigned short* __restrict__ Al,
                                                   const unsigned short* __restrict__ BhT,
                                                   const unsigned short* __restrict__ BlT,
                                                   float* __restrict__ C, int M) {
    const int BM = 128, BN = 128, BK = 32;
    __shared__ unsigned short sAh[BM * BK];   // 8 KB each
    __shared__ unsigned short sAl[BM * BK];
    __shared__ unsigned short sBh[BN * BK];
    __shared__ unsigned short sBl[BN * BK];

    int tid = threadIdx.x;
    int wv = tid >> 6;
    int ln = tid & 63;
    int row0 = blockIdx.x * BM;
    int col0 = blockIdx.y * BN;
    int wr = wv >> 1, wc = wv & 1;        // 2x2 waves, each 64x64
    int fr = ln & 15;                     // fragment row/col
    int ks = (ln >> 4) * 8;               // k-slot (8 bf16 contiguous)

    f32x4 zero = {0.f, 0.f, 0.f, 0.f};
    f32x4 acc[4][4];
    #pragma unroll
    for (int m = 0; m < 4; ++m)
        #pragma unroll
        for (int n = 0; n < 4; ++n) acc[m][n] = zero;

    for (int k0 = 0; k0 < DIM; k0 += BK) {
        __syncthreads();          // previous compute done before overwrite
        #pragma unroll
        for (int p = 0; p < 2; ++p) {
            int f = p * 2048 + tid * 8;        // element index in [128][32] tile
            int r = f >> 5, c = f & 31;
            int arow = row0 + r; if (arow > M - 1) arow = M - 1;
            size_t aoff = (size_t)arow * DIM + k0 + c;
            size_t boff = (size_t)(col0 + r) * DIM + k0 + c;
            int lbyte = p * 4096 + wv * 1024;  // wave-uniform LDS byte offset
            gload16(Ah + aoff, (char*)sAh + lbyte);
            gload16(Al + aoff, (char*)sAl + lbyte);
            gload16(BhT + boff, (char*)sBh + lbyte);
            gload16(BlT + boff, (char*)sBl + lbyte);
        }
        __syncthreads();          // drains vmcnt + lgkmcnt

        bf16x8 ah[4], al[4], bh[4], bl[4];
        #pragma unroll
        for (int m = 0; m < 4; ++m) {
            int r = wr * 64 + m * 16 + fr;
            ah[m] = *reinterpret_cast<const bf16x8*>(&sAh[r * BK + ks]);
            al[m] = *reinterpret_cast<const bf16x8*>(&sAl[r * BK + ks]);
        }
        #pragma unroll
        for (int n = 0; n < 4; ++n) {
            int r = wc * 64 + n * 16 + fr;
            bh[n] = *reinterpret_cast<const bf16x8*>(&sBh[r * BK + ks]);
            bl[n] = *reinterpret_cast<const bf16x8*>(&sBl[r * BK + ks]);
        }
        #pragma unroll
        for (int m = 0; m < 4; ++m)
            #pragma unroll
            for (int n = 0; n < 4; ++n) {
                acc[m][n] = __builtin_amdgcn_mfma_f32_16x16x32_bf16(ah[m], bh[n], acc[m][n], 0, 0, 0);
                acc[m][n] = __builtin_amdgcn_mfma_f32_16x16x32_bf16(al[m], bh[n], acc[m][n], 0, 0, 0);
                acc[m][n] = __builtin_amdgcn_mfma_f32_16x16x32_bf16(ah[m], bl[n], acc[m][n], 0, 0, 0);
            }
    }

    // C/D layout: col = lane&15, row = (lane>>4)*4 + reg
    int rbase = row0 + wr * 64 + (ln >> 4) * 4;
    int cbase = col0 + wc * 64 + (ln & 15);
    #pragma unroll
    for (int m = 0; m < 4; ++m)
        #pragma unroll
        for (int r4 = 0; r4 < 4; ++r4) {
            int row = rbase + m * 16 + r4;
            if (row < M) {
                #pragma unroll
                for (int n = 0; n < 4; ++n)
                    C[(size_t)row * DIM + cbase + n * 16] = acc[m][n][r4];
            }
        }
}

// ---------------- CSR gather aggregation (+bias); epilogue fp32 or relu+bf16-split --------
template<bool SPLIT>
__global__ __launch_bounds__(256) void k_gather(const int* __restrict__ rowptr,
                                                const int* __restrict__ col,
                                                const float* __restrict__ dinv,
                                                const float* __restrict__ pre,
                                                const float* __restrict__ bias,
                                                float* __restrict__ aggf,
                                                unsigned short* __restrict__ oh,
                                                unsigned short* __restrict__ ol) {
    int node = blockIdx.x * 4 + (threadIdx.x >> 6);
    if (node >= N_NODES) return;
    int lane = threadIdx.x & 63;
    int c0 = lane * 4, c1 = 256 + lane * 4;

    float di = dinv[node];
    float w0 = di * di;
    const float* prow = pre + (size_t)node * DIM;
    float4 a0 = *reinterpret_cast<const float4*>(prow + c0);
    float4 a1 = *reinterpret_cast<const float4*>(prow + c1);
    float4 bb0 = *reinterpret_cast<const float4*>(bias + c0);
    float4 bb1 = *reinterpret_cast<const float4*>(bias + c1);
    float4 s0, s1;
    s0.x = fmaf(w0, a0.x, bb0.x); s0.y = fmaf(w0, a0.y, bb0.y);
    s0.z = fmaf(w0, a0.z, bb0.z); s0.w = fmaf(w0, a0.w, bb0.w);
    s1.x = fmaf(w0, a1.x, bb1.x); s1.y = fmaf(w0, a1.y, bb1.y);
    s1.z = fmaf(w0, a1.z, bb1.z); s1.w = fmaf(w0, a1.w, bb1.w);

    int beg = rowptr[node], end = rowptr[node + 1];
    for (int j = beg; j < end; ++j) {
        int src = col[j];
        float w = dinv[src] * di;
        const float* sr = pre + (size_t)src * DIM;
        float4 v0 = *reinterpret_cast<const float4*>(sr + c0);
        float4 v1 = *reinterpret_cast<const float4*>(sr + c1);
        s0.x = fmaf(w, v0.x, s0.x); s0.y = fmaf(w, v0.y, s0.y);
        s0.z = fmaf(w, v0.z, s0.z); s0.w = fmaf(w, v0.w, s0.w);
        s1.x = fmaf(w, v1.x, s1.x); s1.y = fmaf(w, v1.y, s1.y);
        s1.z = fmaf(w, v1.z, s1.z); s1.w = fmaf(w, v1.w, s1.w);
    }
    if (!SPLIT) {
        float* orow = aggf + (size_t)node * DIM;
        *reinterpret_cast<float4*>(orow + c0) = s0;
        *reinterpret_cast<float4*>(orow + c1) = s1;
    } else {
        s0.x = fmaxf(s0.x, 0.f); s0.y = fmaxf(s0.y, 0.f);
        s0.z = fmaxf(s0.z, 0.f); s0.w = fmaxf(s0.w, 0.f);
        s1.x = fmaxf(s1.x, 0.f); s1.y = fmaxf(s1.y, 0.f);
        s1.z = fmaxf(s1.z, 0.f); s1.w = fmaxf(s1.w, 0.f);
        ush4 h0, l0, h1, l1;
        split1(s0.x, h0.x, l0.x); split1(s0.y, h0.y, l0.y);
        split1(s0.z, h0.z, l0.z); split1(s0.w, h0.w, l0.w);
        split1(s1.x, h1.x, l1.x); split1(s1.y, h1.y, l1.y);
        split1(s1.z, h1.z, l1.z); split1(s1.w, h1.w, l1.w);
        size_t base = (size_t)node * DIM;
        *reinterpret_cast<ush4*>(oh + base + c0) = h0;
        *reinterpret_cast<ush4*>(ol + base + c0) = l0;
        *reinterpret_cast<ush4*>(oh + base + c1) = h1;
        *reinterpret_cast<ush4*>(ol + base + c1) = l1;
    }
}

// ---------------- fused pool + output ----------------
__global__ __launch_bounds__(128) void k_pool_out(const float* __restrict__ h,
                                                  const int* __restrict__ seg,
                                                  float* __restrict__ out) {
    int s = blockIdx.x;
    int c = threadIdx.x * 4;
    float* orow = out + (size_t)s * 1024;
    float4 r = *reinterpret_cast<const float4*>(h + (size_t)s * DIM + c);
    *reinterpret_cast<float4*>(orow + c) = r;

    int beg = seg[s], end = seg[s + 1];
    float4 acc = make_float4(0.f, 0.f, 0.f, 0.f);
    for (int v = beg; v < end; ++v) {
        float4 t = *reinterpret_cast<const float4*>(h + (size_t)(NRSU + v) * DIM + c);
        acc.x += t.x; acc.y += t.y; acc.z += t.z; acc.w += t.w;
    }
    float inv = 1.0f / fmaxf((float)(end - beg), 1.0f);
    acc.x *= inv; acc.y *= inv; acc.z *= inv; acc.w *= inv;
    *reinterpret_cast<float4*>(orow + 512 + c) = acc;
}

extern "C" void kernel_launch(void* const* d_in, const int* in_sizes, int n_in,
                              void* d_out, int out_size, void* d_ws, size_t ws_size,
                              hipStream_t stream) {
    const float* x     = (const float*)d_in[0];
    const int*   ei    = (const int*)d_in[1];
    const int*   batch = (const int*)d_in[2];
    const float* W1    = (const float*)d_in[3];
    const float* b1    = (const float*)d_in[4];
    const float* W2    = (const float*)d_in[5];
    const float* b2    = (const float*)d_in[6];
    float* out = (float*)d_out;

    char* ws = (char*)d_ws;
    const size_t HALF = (size_t)N_NODES * DIM * 2;        // 51,200,000 B (one bf16 plane)
    // Region R0 (102.4 MB): Ah|Al bf16 planes; reused at the end as H (fp32)
    unsigned short* Ah = (unsigned short*)(ws);
    unsigned short* Al = (unsigned short*)(ws + HALF);
    float* H           = (float*)(ws);
    // Region R1 (102.4 MB): GEMM output C (fp32)
    float* C = (float*)(ws + 2 * HALF);
    // Small buffers
    char* p = ws + 4 * HALF;
    float* dinv   = (float*)p;                 p += (size_t)N_NODES * 4;
    int*   cnt    = (int*)p;                   p += (size_t)N_NODES * 4;
    int*   rowptr = (int*)p;                   p += (size_t)(N_NODES + 4) * 4;
    int*   col    = (int*)p;                   p += (size_t)E_EDGES * 4;
    int*   bsum   = (int*)p;                   p += 1024;
    int*   seg    = (int*)p;                   p += (size_t)(NRSU + 4) * 4;
    unsigned short* W1h = (unsigned short*)p;  p += (size_t)DIM * DIM * 2;
    unsigned short* W1l = (unsigned short*)p;  p += (size_t)DIM * DIM * 2;
    unsigned short* W2h = (unsigned short*)p;  p += (size_t)DIM * DIM * 2;
    unsigned short* W2l = (unsigned short*)p;  p += (size_t)DIM * DIM * 2;

    dim3 blk(256);
    const int gN = (N_NODES + 255) / 256;
    const int gE = (E_EDGES + 255) / 256;

    // ---- CSR build + norm + weight prep + x split ----
    k_zero_int <<<gN, blk, 0, stream>>>(cnt, N_NODES);
    k_count    <<<gE, blk, 0, stream>>>(ei + E_EDGES, cnt);
    k_scan1    <<<gN, blk, 0, stream>>>(cnt, rowptr, bsum);
    k_scan2    <<<1,  blk, 0, stream>>>(bsum);
    k_scan3    <<<gN, blk, 0, stream>>>(rowptr, bsum);
    k_deg_fin  <<<gN, blk, 0, stream>>>(cnt, dinv);
    k_zero_int <<<gN, blk, 0, stream>>>(cnt, N_NODES);
    k_fill     <<<gE, blk, 0, stream>>>(ei, rowptr, cnt, col);
    k_segbounds<<<((N_NODES - NRSU) + 255) / 256, blk, 0, stream>>>(batch, seg);
    k_wsplit   <<<DIM, blk, 0, stream>>>(W1, W1h, W1l);
    k_wsplit   <<<DIM, blk, 0, stream>>>(W2, W2h, W2l);
    k_split    <<<(int)((size_t)N_NODES * DIM / 4 / 256), blk, 0, stream>>>(x, Ah, Al);

    dim3 ggrid((N_NODES + 127) / 128, DIM / 128);

    // ---- layer 1 ----
    k_gemm_mfma   <<<ggrid, blk, 0, stream>>>(Ah, Al, W1h, W1l, C, N_NODES);
    k_gather<true><<<(N_NODES + 3) / 4, blk, 0, stream>>>(rowptr, col, dinv, C, b1, nullptr, Ah, Al);

    // ---- layer 2 ----
    k_gemm_mfma    <<<ggrid, blk, 0, stream>>>(Ah, Al, W2h, W2l, C, N_NODES);
    k_gather<false><<<(N_NODES + 3) / 4, blk, 0, stream>>>(rowptr, col, dinv, C, b2, H, nullptr, nullptr);

    // ---- pool + output ----
    k_pool_out<<<NRSU, dim3(128), 0, stream>>>(H, seg, out);
}

// Round 5
// 610.571 us; speedup vs baseline: 10.4415x; 1.0056x over previous
//
#include <hip/hip_runtime.h>

#define N_NODES 50000
#define E_EDGES 400000
#define DIM     512
#define NRSU    1000
#define NB_SCAN 196           // ceil(50000/256)

typedef __attribute__((ext_vector_type(8))) __bf16 bf16x8;
typedef __attribute__((ext_vector_type(4))) float  f32x4;

struct __align__(8) ush4 { unsigned short x, y, z, w; };

// ---------- bf16 split helpers (RNE) ----------
__device__ __forceinline__ unsigned short f2bf_rne(float x) {
    unsigned u = __float_as_uint(x);
    unsigned r = u + 0x7fff + ((u >> 16) & 1);
    return (unsigned short)(r >> 16);
}
__device__ __forceinline__ float bf2f(unsigned short b) {
    return __uint_as_float((unsigned)b << 16);
}
__device__ __forceinline__ void split1(float v, unsigned short& h, unsigned short& l) {
    h = f2bf_rne(v);
    l = f2bf_rne(v - bf2f(h));
}

// ---------- async global->LDS (16B per lane) ----------
typedef __attribute__((address_space(1))) const unsigned char ga_u8;
typedef __attribute__((address_space(3))) unsigned char la_u8;
__device__ __forceinline__ void gload16(const void* g, void* l) {
    __builtin_amdgcn_global_load_lds((ga_u8*)g, (la_u8*)l, 16, 0, 0);
}

// ---------------- zero int array ----------------
__global__ void k_zero_int(int* __restrict__ p, int n) {
    int i = blockIdx.x * 256 + threadIdx.x;
    if (i < n) p[i] = 0;
}

// ---------------- in-degree count ----------------
__global__ void k_count(const int* __restrict__ dst, int* __restrict__ cnt) {
    int e = blockIdx.x * 256 + threadIdx.x;
    if (e < E_EDGES) atomicAdd(&cnt[dst[e]], 1);
}

// ---------------- block-wise exclusive scan ----------------
__global__ __launch_bounds__(256) void k_scan1(const int* __restrict__ cnt,
                                               int* __restrict__ rowptr,
                                               int* __restrict__ bsum) {
    __shared__ int sh[256];
    int tid = threadIdx.x;
    int i = blockIdx.x * 256 + tid;
    int v = (i < N_NODES) ? cnt[i] : 0;
    sh[tid] = v;
    __syncthreads();
    #pragma unroll
    for (int off = 1; off < 256; off <<= 1) {
        int t = (tid >= off) ? sh[tid - off] : 0;
        __syncthreads();
        sh[tid] += t;
        __syncthreads();
    }
    if (i < N_NODES) rowptr[i] = sh[tid] - v;
    if (tid == 255) bsum[blockIdx.x] = sh[255];
}

__global__ __launch_bounds__(256) void k_scan2(int* __restrict__ bsum) {
    __shared__ int sh[256];
    int tid = threadIdx.x;
    int v = (tid < NB_SCAN) ? bsum[tid] : 0;
    sh[tid] = v;
    __syncthreads();
    #pragma unroll
    for (int off = 1; off < 256; off <<= 1) {
        int t = (tid >= off) ? sh[tid - off] : 0;
        __syncthreads();
        sh[tid] += t;
        __syncthreads();
    }
    if (tid < NB_SCAN) bsum[tid] = sh[tid] - v;
}

// scan finalize + dinv + zero fill counters (merged)
__global__ void k_scan3(int* __restrict__ rowptr, const int* __restrict__ bsum,
                        int* __restrict__ cntfill, float* __restrict__ dinv) {
    int i = blockIdx.x * 256 + threadIdx.x;
    if (i < N_NODES) {
        rowptr[i] += bsum[blockIdx.x];
        int c = cntfill[i];
        dinv[i] = rsqrtf((float)c + 1.0f);   // self-loop
        cntfill[i] = 0;                      // becomes fill counter
    }
    if (i == 0) rowptr[N_NODES] = E_EDGES;
}

// ---------------- CSR fill ----------------
__global__ void k_fill(const int* __restrict__ ei, const int* __restrict__ rowptr,
                       int* __restrict__ fill, int* __restrict__ col) {
    int e = blockIdx.x * 256 + threadIdx.x;
    if (e >= E_EDGES) return;
    int s = ei[e];
    int d = ei[E_EDGES + e];
    int p = atomicAdd(&fill[d], 1);
    col[rowptr[d] + p] = s;
}

// ---------------- segment boundaries (batch monotone over vehicles) ----
__global__ void k_segbounds(const int* __restrict__ batch, int* __restrict__ seg) {
    const int n_veh = N_NODES - NRSU;
    int v = blockIdx.x * 256 + threadIdx.x;
    if (v >= n_veh) return;
    int b = batch[NRSU + v];
    if (v == 0) {
        for (int s = 0; s <= b; ++s) seg[s] = 0;
    } else {
        int bp = batch[NRSU + v - 1];
        for (int s = bp + 1; s <= b; ++s) seg[s] = v;
    }
    if (v == n_veh - 1) {
        for (int s = b + 1; s <= NRSU; ++s) seg[s] = n_veh;
    }
}

// ---------------- both W [K][N] -> W^T split bf16 hi/lo [N][K] ----------------
__global__ void k_wsplit(const float* __restrict__ W1, const float* __restrict__ W2,
                         unsigned short* __restrict__ W1h, unsigned short* __restrict__ W1l,
                         unsigned short* __restrict__ W2h, unsigned short* __restrict__ W2l) {
    const float* W = blockIdx.y ? W2 : W1;
    unsigned short* Wh = blockIdx.y ? W2h : W1h;
    unsigned short* Wl = blockIdx.y ? W2l : W1l;
    int n = blockIdx.x;
    for (int k = threadIdx.x; k < DIM; k += 256) {
        float v = W[(size_t)k * DIM + n];
        unsigned short h, l;
        split1(v, h, l);
        Wh[(size_t)n * DIM + k] = h;
        Wl[(size_t)n * DIM + k] = l;
    }
}

// ---------------- x -> bf16 hi/lo split ----------------
__global__ void k_split(const float* __restrict__ in,
                        unsigned short* __restrict__ hi,
                        unsigned short* __restrict__ lo) {
    size_t i = ((size_t)blockIdx.x * 256 + threadIdx.x) * 4;
    float4 v = *reinterpret_cast<const float4*>(in + i);
    ush4 h, l;
    split1(v.x, h.x, l.x);
    split1(v.y, h.y, l.y);
    split1(v.z, h.z, l.z);
    split1(v.w, h.w, l.w);
    *reinterpret_cast<ush4*>(hi + i) = h;
    *reinterpret_cast<ush4*>(lo + i) = l;
}

// ---------------- split-bf16 MFMA GEMM with XOR-swizzled LDS ----------------
// LDS logical layout: row r (0..127) x 4 slots of 8 bf16; slot s holds global
// k-chunk (s ^ (r&3)). Staging keeps LDS dest linear (global_load_lds) and
// pre-swizzles the global source k-offset; reads apply the same involution.
__global__ __launch_bounds__(256) void k_gemm_mfma(const unsigned short* __restrict__ Ah,
                                                   const unsigned short* __restrict__ Al,
                                                   const unsigned short* __restrict__ BhT,
                                                   const unsigned short* __restrict__ BlT,
                                                   float* __restrict__ C, int M) {
    const int BM = 128, BN = 128, BK = 32;
    __shared__ unsigned short sAh[BM * BK];
    __shared__ unsigned short sAl[BM * BK];
    __shared__ unsigned short sBh[BN * BK];
    __shared__ unsigned short sBl[BN * BK];

    int tid = threadIdx.x;
    int wv = tid >> 6;
    int ln = tid & 63;
    int row0 = blockIdx.x * BM;
    int col0 = blockIdx.y * BN;
    int wr = wv >> 1, wc = wv & 1;        // 2x2 waves, each 64x64
    int fr = ln & 15;
    int ks16 = ln >> 4;                   // k-chunk 0..3

    f32x4 zero = {0.f, 0.f, 0.f, 0.f};
    f32x4 acc[4][4];
    #pragma unroll
    for (int m = 0; m < 4; ++m)
        #pragma unroll
        for (int n = 0; n < 4; ++n) acc[m][n] = zero;

    for (int k0 = 0; k0 < DIM; k0 += BK) {
        __syncthreads();
        #pragma unroll
        for (int p = 0; p < 2; ++p) {
            int idx = p * 256 + tid;           // (row, slot) id: row = idx>>2, slot = idx&3
            int r = idx >> 2;
            int slot = idx & 3;
            int c = ((slot ^ (r & 3)) << 3);   // pre-swizzled global k-chunk
            int arow = row0 + r; if (arow > M - 1) arow = M - 1;
            size_t aoff = (size_t)arow * DIM + k0 + c;
            size_t boff = (size_t)(col0 + r) * DIM + k0 + c;
            int lbyte = p * 4096 + wv * 1024;  // linear wave-uniform LDS dest
            gload16(Ah + aoff, (char*)sAh + lbyte);
            gload16(Al + aoff, (char*)sAl + lbyte);
            gload16(BhT + boff, (char*)sBh + lbyte);
            gload16(BlT + boff, (char*)sBl + lbyte);
        }
        __syncthreads();

        bf16x8 ah[4], al[4], bh[4], bl[4];
        #pragma unroll
        for (int m = 0; m < 4; ++m) {
            int r = wr * 64 + m * 16 + fr;
            int e = r * BK + ((ks16 ^ (r & 3)) << 3);
            ah[m] = *reinterpret_cast<const bf16x8*>(&sAh[e]);
            al[m] = *reinterpret_cast<const bf16x8*>(&sAl[e]);
        }
        #pragma unroll
        for (int n = 0; n < 4; ++n) {
            int r = wc * 64 + n * 16 + fr;
            int e = r * BK + ((ks16 ^ (r & 3)) << 3);
            bh[n] = *reinterpret_cast<const bf16x8*>(&sBh[e]);
            bl[n] = *reinterpret_cast<const bf16x8*>(&sBl[e]);
        }
        #pragma unroll
        for (int m = 0; m < 4; ++m)
            #pragma unroll
            for (int n = 0; n < 4; ++n) {
                acc[m][n] = __builtin_amdgcn_mfma_f32_16x16x32_bf16(ah[m], bh[n], acc[m][n], 0, 0, 0);
                acc[m][n] = __builtin_amdgcn_mfma_f32_16x16x32_bf16(al[m], bh[n], acc[m][n], 0, 0, 0);
                acc[m][n] = __builtin_amdgcn_mfma_f32_16x16x32_bf16(ah[m], bl[n], acc[m][n], 0, 0, 0);
            }
    }

    int rbase = row0 + wr * 64 + (ln >> 4) * 4;
    int cbase = col0 + wc * 64 + (ln & 15);
    #pragma unroll
    for (int m = 0; m < 4; ++m)
        #pragma unroll
        for (int r4 = 0; r4 < 4; ++r4) {
            int row = rbase + m * 16 + r4;
            if (row < M) {
                #pragma unroll
                for (int n = 0; n < 4; ++n)
                    C[(size_t)row * DIM + cbase + n * 16] = acc[m][n][r4];
            }
        }
}

// ---------------- CSR gather aggregation, MLP-optimized ----------------
#define FMA4(d, ww, v) d.x = fmaf(ww, v.x, d.x); d.y = fmaf(ww, v.y, d.y); \
                       d.z = fmaf(ww, v.z, d.z); d.w = fmaf(ww, v.w, d.w)

template<bool SPLIT>
__global__ __launch_bounds__(256) void k_gather(const int* __restrict__ rowptr,
                                                const int* __restrict__ col,
                                                const float* __restrict__ dinv,
                                                const float* __restrict__ pre,
                                                const float* __restrict__ bias,
                                                float* __restrict__ aggf,
                                                unsigned short* __restrict__ oh,
                                                unsigned short* __restrict__ ol) {
    int node = blockIdx.x * 4 + (threadIdx.x >> 6);
    if (node >= N_NODES) return;
    int lane = threadIdx.x & 63;
    int c0 = lane * 4, c1 = 256 + lane * 4;

    float di = dinv[node];
    float w0 = di * di;
    const float* prow = pre + (size_t)node * DIM;
    float4 a0 = *reinterpret_cast<const float4*>(prow + c0);
    float4 a1 = *reinterpret_cast<const float4*>(prow + c1);
    float4 bb0 = *reinterpret_cast<const float4*>(bias + c0);
    float4 bb1 = *reinterpret_cast<const float4*>(bias + c1);
    float4 s0, s1;
    s0.x = fmaf(w0, a0.x, bb0.x); s0.y = fmaf(w0, a0.y, bb0.y);
    s0.z = fmaf(w0, a0.z, bb0.z); s0.w = fmaf(w0, a0.w, bb0.w);
    s1.x = fmaf(w0, a1.x, bb1.x); s1.y = fmaf(w0, a1.y, bb1.y);
    s1.z = fmaf(w0, a1.z, bb1.z); s1.w = fmaf(w0, a1.w, bb1.w);
    float4 t0 = make_float4(0.f, 0.f, 0.f, 0.f);
    float4 t1 = make_float4(0.f, 0.f, 0.f, 0.f);

    int beg = rowptr[node], end = rowptr[node + 1];
    int deg = end - beg;
    for (int j0 = 0; j0 < deg; j0 += 64) {
        // coalesced prefetch of up to 64 neighbor ids + weights
        int j = j0 + lane;
        int cj = 0; float wj = 0.f;
        if (j < deg) { cj = col[beg + j]; wj = dinv[cj] * di; }
        int lim = deg - j0; if (lim > 64) lim = 64;
        int jj = 0;
        for (; jj + 4 <= lim; jj += 4) {
            int  sa = __shfl(cj, jj);     float wa = __shfl(wj, jj);
            int  sb = __shfl(cj, jj + 1); float wb = __shfl(wj, jj + 1);
            int  sc = __shfl(cj, jj + 2); float wcc = __shfl(wj, jj + 2);
            int  sd = __shfl(cj, jj + 3); float wdd = __shfl(wj, jj + 3);
            const float* ra = pre + (size_t)sa * DIM;
            const float* rb = pre + (size_t)sb * DIM;
            const float* rc = pre + (size_t)sc * DIM;
            const float* rd = pre + (size_t)sd * DIM;
            float4 va0 = *reinterpret_cast<const float4*>(ra + c0);
            float4 va1 = *reinterpret_cast<const float4*>(ra + c1);
            float4 vb0 = *reinterpret_cast<const float4*>(rb + c0);
            float4 vb1 = *reinterpret_cast<const float4*>(rb + c1);
            float4 vc0 = *reinterpret_cast<const float4*>(rc + c0);
            float4 vc1 = *reinterpret_cast<const float4*>(rc + c1);
            float4 vd0 = *reinterpret_cast<const float4*>(rd + c0);
            float4 vd1 = *reinterpret_cast<const float4*>(rd + c1);
            FMA4(s0, wa, va0); FMA4(s1, wa, va1);
            FMA4(t0, wb, vb0); FMA4(t1, wb, vb1);
            FMA4(s0, wcc, vc0); FMA4(s1, wcc, vc1);
            FMA4(t0, wdd, vd0); FMA4(t1, wdd, vd1);
        }
        for (; jj < lim; ++jj) {
            int sa = __shfl(cj, jj); float wa = __shfl(wj, jj);
            const float* ra = pre + (size_t)sa * DIM;
            float4 va0 = *reinterpret_cast<const float4*>(ra + c0);
            float4 va1 = *reinterpret_cast<const float4*>(ra + c1);
            FMA4(s0, wa, va0); FMA4(s1, wa, va1);
        }
    }
    s0.x += t0.x; s0.y += t0.y; s0.z += t0.z; s0.w += t0.w;
    s1.x += t1.x; s1.y += t1.y; s1.z += t1.z; s1.w += t1.w;

    if (!SPLIT) {
        float* orow = aggf + (size_t)node * DIM;
        *reinterpret_cast<float4*>(orow + c0) = s0;
        *reinterpret_cast<float4*>(orow + c1) = s1;
    } else {
        s0.x = fmaxf(s0.x, 0.f); s0.y = fmaxf(s0.y, 0.f);
        s0.z = fmaxf(s0.z, 0.f); s0.w = fmaxf(s0.w, 0.f);
        s1.x = fmaxf(s1.x, 0.f); s1.y = fmaxf(s1.y, 0.f);
        s1.w = fmaxf(s1.w, 0.f); s1.z = fmaxf(s1.z, 0.f);
        ush4 h0, l0, h1, l1;
        split1(s0.x, h0.x, l0.x); split1(s0.y, h0.y, l0.y);
        split1(s0.z, h0.z, l0.z); split1(s0.w, h0.w, l0.w);
        split1(s1.x, h1.x, l1.x); split1(s1.y, h1.y, l1.y);
        split1(s1.z, h1.z, l1.z); split1(s1.w, h1.w, l1.w);
        size_t base = (size_t)node * DIM;
        *reinterpret_cast<ush4*>(oh + base + c0) = h0;
        *reinterpret_cast<ush4*>(ol + base + c0) = l0;
        *reinterpret_cast<ush4*>(oh + base + c1) = h1;
        *reinterpret_cast<ush4*>(ol + base + c1) = l1;
    }
}

// ---------------- fused pool + output ----------------
__global__ __launch_bounds__(128) void k_pool_out(const float* __restrict__ h,
                                                  const int* __restrict__ seg,
                                                  float* __restrict__ out) {
    int s = blockIdx.x;
    int c = threadIdx.x * 4;
    float* orow = out + (size_t)s * 1024;
    float4 r = *reinterpret_cast<const float4*>(h + (size_t)s * DIM + c);
    *reinterpret_cast<float4*>(orow + c) = r;

    int beg = seg[s], end = seg[s + 1];
    float4 acc = make_float4(0.f, 0.f, 0.f, 0.f);
    for (int v = beg; v < end; ++v) {
        float4 t = *reinterpret_cast<const float4*>(h + (size_t)(NRSU + v) * DIM + c);
        acc.x += t.x; acc.y += t.y; acc.z += t.z; acc.w += t.w;
    }
    float inv = 1.0f / fmaxf((float)(end - beg), 1.0f);
    acc.x *= inv; acc.y *= inv; acc.z *= inv; acc.w *= inv;
    *reinterpret_cast<float4*>(orow + 512 + c) = acc;
}

extern "C" void kernel_launch(void* const* d_in, const int* in_sizes, int n_in,
                              void* d_out, int out_size, void* d_ws, size_t ws_size,
                              hipStream_t stream) {
    const float* x     = (const float*)d_in[0];
    const int*   ei    = (const int*)d_in[1];
    const int*   batch = (const int*)d_in[2];
    const float* W1    = (const float*)d_in[3];
    const float* b1    = (const float*)d_in[4];
    const float* W2    = (const float*)d_in[5];
    const float* b2    = (const float*)d_in[6];
    float* out = (float*)d_out;

    char* ws = (char*)d_ws;
    const size_t HALF = (size_t)N_NODES * DIM * 2;        // one bf16 plane
    unsigned short* Ah = (unsigned short*)(ws);
    unsigned short* Al = (unsigned short*)(ws + HALF);
    float* H           = (float*)(ws);                    // aliases Ah/Al (final layer)
    float* C = (float*)(ws + 2 * HALF);
    char* p = ws + 4 * HALF;
    float* dinv   = (float*)p;                 p += (size_t)N_NODES * 4;
    int*   cnt    = (int*)p;                   p += (size_t)N_NODES * 4;   // reused as fill
    int*   rowptr = (int*)p;                   p += (size_t)(N_NODES + 4) * 4;
    int*   col    = (int*)p;                   p += (size_t)E_EDGES * 4;
    int*   bsum   = (int*)p;                   p += 1024;
    int*   seg    = (int*)p;                   p += (size_t)(NRSU + 4) * 4;
    unsigned short* W1h = (unsigned short*)p;  p += (size_t)DIM * DIM * 2;
    unsigned short* W1l = (unsigned short*)p;  p += (size_t)DIM * DIM * 2;
    unsigned short* W2h = (unsigned short*)p;  p += (size_t)DIM * DIM * 2;
    unsigned short* W2l = (unsigned short*)p;  p += (size_t)DIM * DIM * 2;

    dim3 blk(256);
    const int gN = (N_NODES + 255) / 256;
    const int gE = (E_EDGES + 255) / 256;

    // ---- CSR build + norm + weight prep + x split ----
    k_zero_int <<<gN, blk, 0, stream>>>(cnt, N_NODES);
    k_count    <<<gE, blk, 0, stream>>>(ei + E_EDGES, cnt);
    k_scan1    <<<gN, blk, 0, stream>>>(cnt, rowptr, bsum);
    k_scan2    <<<1,  blk, 0, stream>>>(bsum);
    k_scan3    <<<gN, blk, 0, stream>>>(rowptr, bsum, cnt, dinv);
    k_fill     <<<gE, blk, 0, stream>>>(ei, rowptr, cnt, col);
    k_segbounds<<<((N_NODES - NRSU) + 255) / 256, blk, 0, stream>>>(batch, seg);
    k_wsplit   <<<dim3(DIM, 2), blk, 0, stream>>>(W1, W2, W1h, W1l, W2h, W2l);
    k_split    <<<(int)((size_t)N_NODES * DIM / 4 / 256), blk, 0, stream>>>(x, Ah, Al);

    dim3 ggrid((N_NODES + 127) / 128, DIM / 128);

    // ---- layer 1 ----
    k_gemm_mfma   <<<ggrid, blk, 0, stream>>>(Ah, Al, W1h, W1l, C, N_NODES);
    k_gather<true><<<(N_NODES + 3) / 4, blk, 0, stream>>>(rowptr, col, dinv, C, b1, nullptr, Ah, Al);

    // ---- layer 2 ----
    k_gemm_mfma    <<<ggrid, blk, 0, stream>>>(Ah, Al, W2h, W2l, C, N_NODES);
    k_gather<false><<<(N_NODES + 3) / 4, blk, 0, stream>>>(rowptr, col, dinv, C, b2, H, nullptr, nullptr);

    // ---- pool + output ----
    k_pool_out<<<NRSU, dim3(128), 0, stream>>>(H, seg, out);
}

// Round 6
// 602.059 us; speedup vs baseline: 10.5891x; 1.0141x over previous
//
#include <hip/hip_runtime.h>

#define N_NODES 50000
#define E_EDGES 400000
#define DIM     512
#define NRSU    1000
#define NB_SCAN 196           // ceil(50000/256)

typedef __attribute__((ext_vector_type(8))) __bf16 bf16x8;
typedef __attribute__((ext_vector_type(4))) float  f32x4;

struct __align__(8) ush4 { unsigned short x, y, z, w; };

// ---------- bf16 split helpers (RNE) ----------
__device__ __forceinline__ unsigned short f2bf_rne(float x) {
    unsigned u = __float_as_uint(x);
    unsigned r = u + 0x7fff + ((u >> 16) & 1);
    return (unsigned short)(r >> 16);
}
__device__ __forceinline__ float bf2f(unsigned short b) {
    return __uint_as_float((unsigned)b << 16);
}
__device__ __forceinline__ void split1(float v, unsigned short& h, unsigned short& l) {
    h = f2bf_rne(v);
    l = f2bf_rne(v - bf2f(h));
}

// ---------- async global->LDS (16B per lane) ----------
typedef __attribute__((address_space(1))) const unsigned char ga_u8;
typedef __attribute__((address_space(3))) unsigned char la_u8;
__device__ __forceinline__ void gload16(const void* g, void* l) {
    __builtin_amdgcn_global_load_lds((ga_u8*)g, (la_u8*)l, 16, 0, 0);
}

// ---------------- zero int array ----------------
__global__ void k_zero_int(int* __restrict__ p, int n) {
    int i = blockIdx.x * 256 + threadIdx.x;
    if (i < n) p[i] = 0;
}

// ---------------- in-degree count ----------------
__global__ void k_count(const int* __restrict__ dst, int* __restrict__ cnt) {
    int e = blockIdx.x * 256 + threadIdx.x;
    if (e < E_EDGES) atomicAdd(&cnt[dst[e]], 1);
}

// ---------------- block-wise exclusive scan ----------------
__global__ __launch_bounds__(256) void k_scan1(const int* __restrict__ cnt,
                                               int* __restrict__ rowptr,
                                               int* __restrict__ bsum) {
    __shared__ int sh[256];
    int tid = threadIdx.x;
    int i = blockIdx.x * 256 + tid;
    int v = (i < N_NODES) ? cnt[i] : 0;
    sh[tid] = v;
    __syncthreads();
    #pragma unroll
    for (int off = 1; off < 256; off <<= 1) {
        int t = (tid >= off) ? sh[tid - off] : 0;
        __syncthreads();
        sh[tid] += t;
        __syncthreads();
    }
    if (i < N_NODES) rowptr[i] = sh[tid] - v;
    if (tid == 255) bsum[blockIdx.x] = sh[255];
}

__global__ __launch_bounds__(256) void k_scan2(int* __restrict__ bsum) {
    __shared__ int sh[256];
    int tid = threadIdx.x;
    int v = (tid < NB_SCAN) ? bsum[tid] : 0;
    sh[tid] = v;
    __syncthreads();
    #pragma unroll
    for (int off = 1; off < 256; off <<= 1) {
        int t = (tid >= off) ? sh[tid - off] : 0;
        __syncthreads();
        sh[tid] += t;
        __syncthreads();
    }
    if (tid < NB_SCAN) bsum[tid] = sh[tid] - v;
}

// scan finalize + dinv + zero fill counters (merged)
__global__ void k_scan3(int* __restrict__ rowptr, const int* __restrict__ bsum,
                        int* __restrict__ cntfill, float* __restrict__ dinv) {
    int i = blockIdx.x * 256 + threadIdx.x;
    if (i < N_NODES) {
        rowptr[i] += bsum[blockIdx.x];
        int c = cntfill[i];
        dinv[i] = rsqrtf((float)c + 1.0f);   // self-loop
        cntfill[i] = 0;                      // becomes fill counter
    }
    if (i == 0) rowptr[N_NODES] = E_EDGES;
}

// ---------------- CSR fill (+ precomputed edge weights) ----------------
__global__ void k_fill(const int* __restrict__ ei, const int* __restrict__ rowptr,
                       int* __restrict__ fill, int* __restrict__ col,
                       const float* __restrict__ dinv, float* __restrict__ wnorm) {
    int e = blockIdx.x * 256 + threadIdx.x;
    if (e >= E_EDGES) return;
    int s = ei[e];
    int d = ei[E_EDGES + e];
    int p = atomicAdd(&fill[d], 1);
    int idx = rowptr[d] + p;
    col[idx] = s;
    wnorm[idx] = dinv[s] * dinv[d];
}

// ---------------- segment boundaries (batch monotone over vehicles) ----
__global__ void k_segbounds(const int* __restrict__ batch, int* __restrict__ seg) {
    const int n_veh = N_NODES - NRSU;
    int v = blockIdx.x * 256 + threadIdx.x;
    if (v >= n_veh) return;
    int b = batch[NRSU + v];
    if (v == 0) {
        for (int s = 0; s <= b; ++s) seg[s] = 0;
    } else {
        int bp = batch[NRSU + v - 1];
        for (int s = bp + 1; s <= b; ++s) seg[s] = v;
    }
    if (v == n_veh - 1) {
        for (int s = b + 1; s <= NRSU; ++s) seg[s] = n_veh;
    }
}

// ---------------- both W [K][N] -> W^T split bf16 hi/lo [N][K] ----------------
__global__ void k_wsplit(const float* __restrict__ W1, const float* __restrict__ W2,
                         unsigned short* __restrict__ W1h, unsigned short* __restrict__ W1l,
                         unsigned short* __restrict__ W2h, unsigned short* __restrict__ W2l) {
    const float* W = blockIdx.y ? W2 : W1;
    unsigned short* Wh = blockIdx.y ? W2h : W1h;
    unsigned short* Wl = blockIdx.y ? W2l : W1l;
    int n = blockIdx.x;
    for (int k = threadIdx.x; k < DIM; k += 256) {
        float v = W[(size_t)k * DIM + n];
        unsigned short h, l;
        split1(v, h, l);
        Wh[(size_t)n * DIM + k] = h;
        Wl[(size_t)n * DIM + k] = l;
    }
}

// ---------------- x -> bf16 hi/lo split ----------------
__global__ void k_split(const float* __restrict__ in,
                        unsigned short* __restrict__ hi,
                        unsigned short* __restrict__ lo) {
    size_t i = ((size_t)blockIdx.x * 256 + threadIdx.x) * 4;
    float4 v = *reinterpret_cast<const float4*>(in + i);
    ush4 h, l;
    split1(v.x, h.x, l.x);
    split1(v.y, h.y, l.y);
    split1(v.z, h.z, l.z);
    split1(v.w, h.w, l.w);
    *reinterpret_cast<ush4*>(hi + i) = h;
    *reinterpret_cast<ush4*>(lo + i) = l;
}

// ---------------- split-bf16 MFMA GEMM with XOR-swizzled LDS ----------------
// grid = (col-tiles, row-blocks): consecutive blocks share the A row-panel.
__global__ __launch_bounds__(256) void k_gemm_mfma(const unsigned short* __restrict__ Ah,
                                                   const unsigned short* __restrict__ Al,
                                                   const unsigned short* __restrict__ BhT,
                                                   const unsigned short* __restrict__ BlT,
                                                   float* __restrict__ C, int M) {
    const int BM = 128, BN = 128, BK = 32;
    __shared__ unsigned short sAh[BM * BK];
    __shared__ unsigned short sAl[BM * BK];
    __shared__ unsigned short sBh[BN * BK];
    __shared__ unsigned short sBl[BN * BK];

    int tid = threadIdx.x;
    int wv = tid >> 6;
    int ln = tid & 63;
    int row0 = blockIdx.y * BM;
    int col0 = blockIdx.x * BN;
    int wr = wv >> 1, wc = wv & 1;        // 2x2 waves, each 64x64
    int fr = ln & 15;
    int ks16 = ln >> 4;                   // k-chunk 0..3

    f32x4 zero = {0.f, 0.f, 0.f, 0.f};
    f32x4 acc[4][4];
    #pragma unroll
    for (int m = 0; m < 4; ++m)
        #pragma unroll
        for (int n = 0; n < 4; ++n) acc[m][n] = zero;

    for (int k0 = 0; k0 < DIM; k0 += BK) {
        __syncthreads();
        #pragma unroll
        for (int p = 0; p < 2; ++p) {
            int idx = p * 256 + tid;           // (row, slot): row = idx>>2, slot = idx&3
            int r = idx >> 2;
            int slot = idx & 3;
            int c = ((slot ^ (r & 3)) << 3);   // pre-swizzled global k-chunk
            int arow = row0 + r; if (arow > M - 1) arow = M - 1;
            size_t aoff = (size_t)arow * DIM + k0 + c;
            size_t boff = (size_t)(col0 + r) * DIM + k0 + c;
            int lbyte = p * 4096 + wv * 1024;  // linear wave-uniform LDS dest
            gload16(Ah + aoff, (char*)sAh + lbyte);
            gload16(Al + aoff, (char*)sAl + lbyte);
            gload16(BhT + boff, (char*)sBh + lbyte);
            gload16(BlT + boff, (char*)sBl + lbyte);
        }
        __syncthreads();

        bf16x8 ah[4], al[4], bh[4], bl[4];
        #pragma unroll
        for (int m = 0; m < 4; ++m) {
            int r = wr * 64 + m * 16 + fr;
            int e = r * BK + ((ks16 ^ (r & 3)) << 3);
            ah[m] = *reinterpret_cast<const bf16x8*>(&sAh[e]);
            al[m] = *reinterpret_cast<const bf16x8*>(&sAl[e]);
        }
        #pragma unroll
        for (int n = 0; n < 4; ++n) {
            int r = wc * 64 + n * 16 + fr;
            int e = r * BK + ((ks16 ^ (r & 3)) << 3);
            bh[n] = *reinterpret_cast<const bf16x8*>(&sBh[e]);
            bl[n] = *reinterpret_cast<const bf16x8*>(&sBl[e]);
        }
        #pragma unroll
        for (int m = 0; m < 4; ++m)
            #pragma unroll
            for (int n = 0; n < 4; ++n) {
                acc[m][n] = __builtin_amdgcn_mfma_f32_16x16x32_bf16(ah[m], bh[n], acc[m][n], 0, 0, 0);
                acc[m][n] = __builtin_amdgcn_mfma_f32_16x16x32_bf16(al[m], bh[n], acc[m][n], 0, 0, 0);
                acc[m][n] = __builtin_amdgcn_mfma_f32_16x16x32_bf16(ah[m], bl[n], acc[m][n], 0, 0, 0);
            }
    }

    int rbase = row0 + wr * 64 + (ln >> 4) * 4;
    int cbase = col0 + wc * 64 + (ln & 15);
    #pragma unroll
    for (int m = 0; m < 4; ++m)
        #pragma unroll
        for (int r4 = 0; r4 < 4; ++r4) {
            int row = rbase + m * 16 + r4;
            if (row < M) {
                #pragma unroll
                for (int n = 0; n < 4; ++n)
                    C[(size_t)row * DIM + cbase + n * 16] = acc[m][n][r4];
            }
        }
}

// ---------------- CSR gather aggregation: branchless 8-deep unroll ----------------
#define FMA4(d, ww, v) d.x = fmaf(ww, v.x, d.x); d.y = fmaf(ww, v.y, d.y); \
                       d.z = fmaf(ww, v.z, d.z); d.w = fmaf(ww, v.w, d.w)

template<bool SPLIT>
__global__ __launch_bounds__(256) void k_gather(const int* __restrict__ rowptr,
                                                const int* __restrict__ col,
                                                const float* __restrict__ wnorm,
                                                const float* __restrict__ dinv,
                                                const float* __restrict__ pre,
                                                const float* __restrict__ bias,
                                                float* __restrict__ aggf,
                                                unsigned short* __restrict__ oh,
                                                unsigned short* __restrict__ ol) {
    int node = blockIdx.x * 4 + (threadIdx.x >> 6);
    if (node >= N_NODES) return;
    int lane = threadIdx.x & 63;
    int c0 = lane * 4, c1 = 256 + lane * 4;

    float di = dinv[node];
    float w0 = di * di;
    const float* prow = pre + (size_t)node * DIM;
    float4 a0 = *reinterpret_cast<const float4*>(prow + c0);
    float4 a1 = *reinterpret_cast<const float4*>(prow + c1);
    float4 bb0 = *reinterpret_cast<const float4*>(bias + c0);
    float4 bb1 = *reinterpret_cast<const float4*>(bias + c1);
    float4 s0, s1;
    s0.x = fmaf(w0, a0.x, bb0.x); s0.y = fmaf(w0, a0.y, bb0.y);
    s0.z = fmaf(w0, a0.z, bb0.z); s0.w = fmaf(w0, a0.w, bb0.w);
    s1.x = fmaf(w0, a1.x, bb1.x); s1.y = fmaf(w0, a1.y, bb1.y);
    s1.z = fmaf(w0, a1.z, bb1.z); s1.w = fmaf(w0, a1.w, bb1.w);
    float4 t0 = make_float4(0.f, 0.f, 0.f, 0.f);
    float4 t1 = make_float4(0.f, 0.f, 0.f, 0.f);

    int beg = rowptr[node], end = rowptr[node + 1];
    int deg = end - beg;
    for (int j0 = 0; j0 < deg; j0 += 64) {
        // coalesced prefetch of up to 64 neighbor ids + weights
        int j = j0 + lane;
        int cj = 0; float wj = 0.f;
        if (j < deg) { cj = col[beg + j]; wj = wnorm[beg + j]; }
        int lim = deg - j0; if (lim > 64) lim = 64;
        // branchless chunks of 8: lanes beyond lim carry w=0 (reads row 0, adds 0)
        for (int jj = 0; jj < lim; jj += 8) {
            int sidx[8]; float sw[8];
            #pragma unroll
            for (int q = 0; q < 8; ++q) {
                sidx[q] = __shfl(cj, jj + q);
                sw[q]   = __shfl(wj, jj + q);
            }
            float4 v0[8], v1[8];
            #pragma unroll
            for (int q = 0; q < 8; ++q) {
                const float* r = pre + (size_t)sidx[q] * DIM;
                v0[q] = *reinterpret_cast<const float4*>(r + c0);
                v1[q] = *reinterpret_cast<const float4*>(r + c1);
            }
            #pragma unroll
            for (int q = 0; q < 8; q += 2) {
                FMA4(s0, sw[q], v0[q]);     FMA4(s1, sw[q], v1[q]);
                FMA4(t0, sw[q+1], v0[q+1]); FMA4(t1, sw[q+1], v1[q+1]);
            }
        }
    }
    s0.x += t0.x; s0.y += t0.y; s0.z += t0.z; s0.w += t0.w;
    s1.x += t1.x; s1.y += t1.y; s1.z += t1.z; s1.w += t1.w;

    if (!SPLIT) {
        float* orow = aggf + (size_t)node * DIM;
        *reinterpret_cast<float4*>(orow + c0) = s0;
        *reinterpret_cast<float4*>(orow + c1) = s1;
    } else {
        s0.x = fmaxf(s0.x, 0.f); s0.y = fmaxf(s0.y, 0.f);
        s0.z = fmaxf(s0.z, 0.f); s0.w = fmaxf(s0.w, 0.f);
        s1.x = fmaxf(s1.x, 0.f); s1.y = fmaxf(s1.y, 0.f);
        s1.z = fmaxf(s1.z, 0.f); s1.w = fmaxf(s1.w, 0.f);
        ush4 h0, l0, h1, l1;
        split1(s0.x, h0.x, l0.x); split1(s0.y, h0.y, l0.y);
        split1(s0.z, h0.z, l0.z); split1(s0.w, h0.w, l0.w);
        split1(s1.x, h1.x, l1.x); split1(s1.y, h1.y, l1.y);
        split1(s1.z, h1.z, l1.z); split1(s1.w, h1.w, l1.w);
        size_t base = (size_t)node * DIM;
        *reinterpret_cast<ush4*>(oh + base + c0) = h0;
        *reinterpret_cast<ush4*>(ol + base + c0) = l0;
        *reinterpret_cast<ush4*>(oh + base + c1) = h1;
        *reinterpret_cast<ush4*>(ol + base + c1) = l1;
    }
}

// ---------------- fused pool + output ----------------
__global__ __launch_bounds__(128) void k_pool_out(const float* __restrict__ h,
                                                  const int* __restrict__ seg,
                                                  float* __restrict__ out) {
    int s = blockIdx.x;
    int c = threadIdx.x * 4;
    float* orow = out + (size_t)s * 1024;
    float4 r = *reinterpret_cast<const float4*>(h + (size_t)s * DIM + c);
    *reinterpret_cast<float4*>(orow + c) = r;

    int beg = seg[s], end = seg[s + 1];
    float4 acc = make_float4(0.f, 0.f, 0.f, 0.f);
    for (int v = beg; v < end; ++v) {
        float4 t = *reinterpret_cast<const float4*>(h + (size_t)(NRSU + v) * DIM + c);
        acc.x += t.x; acc.y += t.y; acc.z += t.z; acc.w += t.w;
    }
    float inv = 1.0f / fmaxf((float)(end - beg), 1.0f);
    acc.x *= inv; acc.y *= inv; acc.z *= inv; acc.w *= inv;
    *reinterpret_cast<float4*>(orow + 512 + c) = acc;
}

extern "C" void kernel_launch(void* const* d_in, const int* in_sizes, int n_in,
                              void* d_out, int out_size, void* d_ws, size_t ws_size,
                              hipStream_t stream) {
    const float* x     = (const float*)d_in[0];
    const int*   ei    = (const int*)d_in[1];
    const int*   batch = (const int*)d_in[2];
    const float* W1    = (const float*)d_in[3];
    const float* b1    = (const float*)d_in[4];
    const float* W2    = (const float*)d_in[5];
    const float* b2    = (const float*)d_in[6];
    float* out = (float*)d_out;

    char* ws = (char*)d_ws;
    const size_t HALF = (size_t)N_NODES * DIM * 2;        // one bf16 plane
    unsigned short* Ah = (unsigned short*)(ws);
    unsigned short* Al = (unsigned short*)(ws + HALF);
    float* H           = (float*)(ws);                    // aliases Ah/Al (final layer)
    float* C = (float*)(ws + 2 * HALF);
    char* p = ws + 4 * HALF;
    float* dinv   = (float*)p;                 p += (size_t)N_NODES * 4;
    int*   cnt    = (int*)p;                   p += (size_t)N_NODES * 4;   // reused as fill
    int*   rowptr = (int*)p;                   p += (size_t)(N_NODES + 4) * 4;
    int*   col    = (int*)p;                   p += (size_t)E_EDGES * 4;
    float* wnorm  = (float*)p;                 p += (size_t)E_EDGES * 4;
    int*   bsum   = (int*)p;                   p += 1024;
    int*   seg    = (int*)p;                   p += (size_t)(NRSU + 4) * 4;
    unsigned short* W1h = (unsigned short*)p;  p += (size_t)DIM * DIM * 2;
    unsigned short* W1l = (unsigned short*)p;  p += (size_t)DIM * DIM * 2;
    unsigned short* W2h = (unsigned short*)p;  p += (size_t)DIM * DIM * 2;
    unsigned short* W2l = (unsigned short*)p;  p += (size_t)DIM * DIM * 2;

    dim3 blk(256);
    const int gN = (N_NODES + 255) / 256;
    const int gE = (E_EDGES + 255) / 256;

    // ---- CSR build + norm + weight prep + x split ----
    k_zero_int <<<gN, blk, 0, stream>>>(cnt, N_NODES);
    k_count    <<<gE, blk, 0, stream>>>(ei + E_EDGES, cnt);
    k_scan1    <<<gN, blk, 0, stream>>>(cnt, rowptr, bsum);
    k_scan2    <<<1,  blk, 0, stream>>>(bsum);
    k_scan3    <<<gN, blk, 0, stream>>>(rowptr, bsum, cnt, dinv);
    k_fill     <<<gE, blk, 0, stream>>>(ei, rowptr, cnt, col, dinv, wnorm);
    k_segbounds<<<((N_NODES - NRSU) + 255) / 256, blk, 0, stream>>>(batch, seg);
    k_wsplit   <<<dim3(DIM, 2), blk, 0, stream>>>(W1, W2, W1h, W1l, W2h, W2l);
    k_split    <<<(int)((size_t)N_NODES * DIM / 4 / 256), blk, 0, stream>>>(x, Ah, Al);

    // col-tiles fastest so consecutive blocks share the A row-panel
    dim3 ggrid(DIM / 128, (N_NODES + 127) / 128);

    // ---- layer 1 ----
    k_gemm_mfma   <<<ggrid, blk, 0, stream>>>(Ah, Al, W1h, W1l, C, N_NODES);
    k_gather<true><<<(N_NODES + 3) / 4, blk, 0, stream>>>(rowptr, col, wnorm, dinv, C, b1, nullptr, Ah, Al);

    // ---- layer 2 ----
    k_gemm_mfma    <<<ggrid, blk, 0, stream>>>(Ah, Al, W2h, W2l, C, N_NODES);
    k_gather<false><<<(N_NODES + 3) / 4, blk, 0, stream>>>(rowptr, col, wnorm, dinv, C, b2, H, nullptr, nullptr);

    // ---- pool + output ----
    k_pool_out<<<NRSU, dim3(128), 0, stream>>>(H, seg, out);
}

// Round 7
// 521.631 us; speedup vs baseline: 12.2218x; 1.1542x over previous
//
#include <hip/hip_runtime.h>

#define N_NODES 50000
#define E_EDGES 400000
#define DIM     512
#define NRSU    1000
#define NB_SCAN 196           // ceil(50000/256)

typedef __attribute__((ext_vector_type(8))) __bf16 bf16x8;
typedef __attribute__((ext_vector_type(4))) float  f32x4;

struct __align__(8) ush4 { unsigned short x, y, z, w; };

// ---------- bf16 split helpers (RNE) ----------
__device__ __forceinline__ unsigned short f2bf_rne(float x) {
    unsigned u = __float_as_uint(x);
    unsigned r = u + 0x7fff + ((u >> 16) & 1);
    return (unsigned short)(r >> 16);
}
__device__ __forceinline__ float bf2f(unsigned short b) {
    return __uint_as_float((unsigned)b << 16);
}
__device__ __forceinline__ void split1(float v, unsigned short& h, unsigned short& l) {
    h = f2bf_rne(v);
    l = f2bf_rne(v - bf2f(h));
}

// ---------- async global->LDS (16B per lane) ----------
typedef __attribute__((address_space(1))) const unsigned char ga_u8;
typedef __attribute__((address_space(3))) unsigned char la_u8;
__device__ __forceinline__ void gload16(const void* g, void* l) {
    __builtin_amdgcn_global_load_lds((ga_u8*)g, (la_u8*)l, 16, 0, 0);
}

// ---------------- zero int array ----------------
__global__ void k_zero_int(int* __restrict__ p, int n) {
    int i = blockIdx.x * 256 + threadIdx.x;
    if (i < n) p[i] = 0;
}

// ---------------- in-degree count ----------------
__global__ void k_count(const int* __restrict__ dst, int* __restrict__ cnt) {
    int e = blockIdx.x * 256 + threadIdx.x;
    if (e < E_EDGES) atomicAdd(&cnt[dst[e]], 1);
}

// ---------------- block-wise exclusive scan ----------------
__global__ __launch_bounds__(256) void k_scan1(const int* __restrict__ cnt,
                                               int* __restrict__ rowptr,
                                               int* __restrict__ bsum) {
    __shared__ int sh[256];
    int tid = threadIdx.x;
    int i = blockIdx.x * 256 + tid;
    int v = (i < N_NODES) ? cnt[i] : 0;
    sh[tid] = v;
    __syncthreads();
    #pragma unroll
    for (int off = 1; off < 256; off <<= 1) {
        int t = (tid >= off) ? sh[tid - off] : 0;
        __syncthreads();
        sh[tid] += t;
        __syncthreads();
    }
    if (i < N_NODES) rowptr[i] = sh[tid] - v;
    if (tid == 255) bsum[blockIdx.x] = sh[255];
}

__global__ __launch_bounds__(256) void k_scan2(int* __restrict__ bsum) {
    __shared__ int sh[256];
    int tid = threadIdx.x;
    int v = (tid < NB_SCAN) ? bsum[tid] : 0;
    sh[tid] = v;
    __syncthreads();
    #pragma unroll
    for (int off = 1; off < 256; off <<= 1) {
        int t = (tid >= off) ? sh[tid - off] : 0;
        __syncthreads();
        sh[tid] += t;
        __syncthreads();
    }
    if (tid < NB_SCAN) bsum[tid] = sh[tid] - v;
}

// scan finalize + dinv + zero fill counters (merged)
__global__ void k_scan3(int* __restrict__ rowptr, const int* __restrict__ bsum,
                        int* __restrict__ cntfill, float* __restrict__ dinv) {
    int i = blockIdx.x * 256 + threadIdx.x;
    if (i < N_NODES) {
        rowptr[i] += bsum[blockIdx.x];
        int c = cntfill[i];
        dinv[i] = rsqrtf((float)c + 1.0f);   // self-loop
        cntfill[i] = 0;                      // becomes fill counter
    }
    if (i == 0) rowptr[N_NODES] = E_EDGES;
}

// ---------------- CSR fill (+ precomputed edge weights) ----------------
__global__ void k_fill(const int* __restrict__ ei, const int* __restrict__ rowptr,
                       int* __restrict__ fill, int* __restrict__ col,
                       const float* __restrict__ dinv, float* __restrict__ wnorm) {
    int e = blockIdx.x * 256 + threadIdx.x;
    if (e >= E_EDGES) return;
    int s = ei[e];
    int d = ei[E_EDGES + e];
    int p = atomicAdd(&fill[d], 1);
    int idx = rowptr[d] + p;
    col[idx] = s;
    wnorm[idx] = dinv[s] * dinv[d];
}

// ---------------- segment boundaries (batch monotone over vehicles) ----
__global__ void k_segbounds(const int* __restrict__ batch, int* __restrict__ seg) {
    const int n_veh = N_NODES - NRSU;
    int v = blockIdx.x * 256 + threadIdx.x;
    if (v >= n_veh) return;
    int b = batch[NRSU + v];
    if (v == 0) {
        for (int s = 0; s <= b; ++s) seg[s] = 0;
    } else {
        int bp = batch[NRSU + v - 1];
        for (int s = bp + 1; s <= b; ++s) seg[s] = v;
    }
    if (v == n_veh - 1) {
        for (int s = b + 1; s <= NRSU; ++s) seg[s] = n_veh;
    }
}

// ---------------- both W [K][N] -> W^T split bf16 hi/lo [N][K] ----------------
__global__ void k_wsplit(const float* __restrict__ W1, const float* __restrict__ W2,
                         unsigned short* __restrict__ W1h, unsigned short* __restrict__ W1l,
                         unsigned short* __restrict__ W2h, unsigned short* __restrict__ W2l) {
    const float* W = blockIdx.y ? W2 : W1;
    unsigned short* Wh = blockIdx.y ? W2h : W1h;
    unsigned short* Wl = blockIdx.y ? W2l : W1l;
    int n = blockIdx.x;
    for (int k = threadIdx.x; k < DIM; k += 256) {
        float v = W[(size_t)k * DIM + n];
        unsigned short h, l;
        split1(v, h, l);
        Wh[(size_t)n * DIM + k] = h;
        Wl[(size_t)n * DIM + k] = l;
    }
}

// ---------------- fp32 -> bf16 hi/lo split (vector pass) ----------------
__global__ void k_split(const float* __restrict__ in,
                        unsigned short* __restrict__ hi,
                        unsigned short* __restrict__ lo) {
    size_t i = ((size_t)blockIdx.x * 256 + threadIdx.x) * 4;
    float4 v = *reinterpret_cast<const float4*>(in + i);
    ush4 h, l;
    split1(v.x, h.x, l.x);
    split1(v.y, h.y, l.y);
    split1(v.z, h.z, l.z);
    split1(v.w, h.w, l.w);
    *reinterpret_cast<ush4*>(hi + i) = h;
    *reinterpret_cast<ush4*>(lo + i) = l;
}

// ---------------- split-bf16 MFMA GEMM with XOR-swizzled LDS ----------------
// MODE 0: C[M x 512] plain, 1-D grid with bijective XCD-chunk remap (A-panel L2 reuse)
// MODE 1: M=2000 "[rsu; pooled]" rows -> write into out with concat layout,
//         adding b2[col] * bscale[row].
template<int MODE>
__global__ __launch_bounds__(256) void k_gemm_mfma(const unsigned short* __restrict__ Ah,
                                                   const unsigned short* __restrict__ Al,
                                                   const unsigned short* __restrict__ BhT,
                                                   const unsigned short* __restrict__ BlT,
                                                   float* __restrict__ C, int M,
                                                   const float* __restrict__ bias,
                                                   const float* __restrict__ bscale) {
    const int BM = 128, BN = 128, BK = 32;
    __shared__ unsigned short sAh[BM * BK];
    __shared__ unsigned short sAl[BM * BK];
    __shared__ unsigned short sBh[BN * BK];
    __shared__ unsigned short sBl[BN * BK];

    int tid = threadIdx.x;
    int wv = tid >> 6;
    int ln = tid & 63;

    int wgid;
    if (MODE == 0) {
        // bijective XCD-chunk remap: nwg = 1564 = 8*195 + 4
        const int q = 195, r = 4;
        int id = blockIdx.x;
        int xcd = id & 7, idx = id >> 3;
        wgid = (xcd < r ? xcd * (q + 1) : r * (q + 1) + (xcd - r) * q) + idx;
    } else {
        wgid = blockIdx.x;
    }
    int col0 = (wgid & 3) * BN;        // col fastest: 4 col-tiles share A row-panel
    int row0 = (wgid >> 2) * BM;

    int wr = wv >> 1, wc = wv & 1;     // 2x2 waves, each 64x64
    int fr = ln & 15;
    int ks16 = ln >> 4;                // k-chunk 0..3

    f32x4 zero = {0.f, 0.f, 0.f, 0.f};
    f32x4 acc[4][4];
    #pragma unroll
    for (int m = 0; m < 4; ++m)
        #pragma unroll
        for (int n = 0; n < 4; ++n) acc[m][n] = zero;

    for (int k0 = 0; k0 < DIM; k0 += BK) {
        __syncthreads();
        #pragma unroll
        for (int p = 0; p < 2; ++p) {
            int idx = p * 256 + tid;           // (row, slot): row = idx>>2, slot = idx&3
            int r = idx >> 2;
            int slot = idx & 3;
            int c = ((slot ^ (r & 3)) << 3);   // pre-swizzled global k-chunk
            int arow = row0 + r; if (arow > M - 1) arow = M - 1;
            size_t aoff = (size_t)arow * DIM + k0 + c;
            size_t boff = (size_t)(col0 + r) * DIM + k0 + c;
            int lbyte = p * 4096 + wv * 1024;  // linear wave-uniform LDS dest
            gload16(Ah + aoff, (char*)sAh + lbyte);
            gload16(Al + aoff, (char*)sAl + lbyte);
            gload16(BhT + boff, (char*)sBh + lbyte);
            gload16(BlT + boff, (char*)sBl + lbyte);
        }
        __syncthreads();

        bf16x8 ah[4], al[4], bh[4], bl[4];
        #pragma unroll
        for (int m = 0; m < 4; ++m) {
            int r = wr * 64 + m * 16 + fr;
            int e = r * BK + ((ks16 ^ (r & 3)) << 3);
            ah[m] = *reinterpret_cast<const bf16x8*>(&sAh[e]);
            al[m] = *reinterpret_cast<const bf16x8*>(&sAl[e]);
        }
        #pragma unroll
        for (int n = 0; n < 4; ++n) {
            int r = wc * 64 + n * 16 + fr;
            int e = r * BK + ((ks16 ^ (r & 3)) << 3);
            bh[n] = *reinterpret_cast<const bf16x8*>(&sBh[e]);
            bl[n] = *reinterpret_cast<const bf16x8*>(&sBl[e]);
        }
        #pragma unroll
        for (int m = 0; m < 4; ++m)
            #pragma unroll
            for (int n = 0; n < 4; ++n) {
                acc[m][n] = __builtin_amdgcn_mfma_f32_16x16x32_bf16(ah[m], bh[n], acc[m][n], 0, 0, 0);
                acc[m][n] = __builtin_amdgcn_mfma_f32_16x16x32_bf16(al[m], bh[n], acc[m][n], 0, 0, 0);
                acc[m][n] = __builtin_amdgcn_mfma_f32_16x16x32_bf16(ah[m], bl[n], acc[m][n], 0, 0, 0);
            }
    }

    int rbase = row0 + wr * 64 + (ln >> 4) * 4;
    int cbase = col0 + wc * 64 + (ln & 15);
    #pragma unroll
    for (int m = 0; m < 4; ++m)
        #pragma unroll
        for (int r4 = 0; r4 < 4; ++r4) {
            int row = rbase + m * 16 + r4;
            if (row < M) {
                if (MODE == 0) {
                    #pragma unroll
                    for (int n = 0; n < 4; ++n)
                        C[(size_t)row * DIM + cbase + n * 16] = acc[m][n][r4];
                } else {
                    float bs = bscale[row];
                    float* dst = (row < NRSU) ? (C + (size_t)row * 1024)
                                              : (C + (size_t)(row - NRSU) * 1024 + 512);
                    #pragma unroll
                    for (int n = 0; n < 4; ++n) {
                        int cc = cbase + n * 16;
                        dst[cc] = acc[m][n][r4] + bias[cc] * bs;
                    }
                }
            }
        }
}

// ---------------- CSR gather aggregation: branchless 8-deep unroll ----------------
#define FMA4(d, ww, v) d.x = fmaf(ww, v.x, d.x); d.y = fmaf(ww, v.y, d.y); \
                       d.z = fmaf(ww, v.z, d.z); d.w = fmaf(ww, v.w, d.w)

// out = S_norm * pre  (+bias, +relu for layer 1); fp32 in/out
template<bool BIASRELU>
__global__ __launch_bounds__(256) void k_gather(const int* __restrict__ rowptr,
                                                const int* __restrict__ col,
                                                const float* __restrict__ wnorm,
                                                const float* __restrict__ dinv,
                                                const float* __restrict__ pre,
                                                const float* __restrict__ bias,
                                                float* __restrict__ outf) {
    int node = blockIdx.x * 4 + (threadIdx.x >> 6);
    if (node >= N_NODES) return;
    int lane = threadIdx.x & 63;
    int c0 = lane * 4, c1 = 256 + lane * 4;

    float di = dinv[node];
    float w0 = di * di;
    const float* prow = pre + (size_t)node * DIM;
    float4 a0 = *reinterpret_cast<const float4*>(prow + c0);
    float4 a1 = *reinterpret_cast<const float4*>(prow + c1);
    float4 s0, s1;
    if (BIASRELU) {
        float4 bb0 = *reinterpret_cast<const float4*>(bias + c0);
        float4 bb1 = *reinterpret_cast<const float4*>(bias + c1);
        s0.x = fmaf(w0, a0.x, bb0.x); s0.y = fmaf(w0, a0.y, bb0.y);
        s0.z = fmaf(w0, a0.z, bb0.z); s0.w = fmaf(w0, a0.w, bb0.w);
        s1.x = fmaf(w0, a1.x, bb1.x); s1.y = fmaf(w0, a1.y, bb1.y);
        s1.z = fmaf(w0, a1.z, bb1.z); s1.w = fmaf(w0, a1.w, bb1.w);
    } else {
        s0.x = w0 * a0.x; s0.y = w0 * a0.y; s0.z = w0 * a0.z; s0.w = w0 * a0.w;
        s1.x = w0 * a1.x; s1.y = w0 * a1.y; s1.z = w0 * a1.z; s1.w = w0 * a1.w;
    }
    float4 t0 = make_float4(0.f, 0.f, 0.f, 0.f);
    float4 t1 = make_float4(0.f, 0.f, 0.f, 0.f);

    int beg = rowptr[node], end = rowptr[node + 1];
    int deg = end - beg;
    for (int j0 = 0; j0 < deg; j0 += 64) {
        int j = j0 + lane;
        int cj = 0; float wj = 0.f;
        if (j < deg) { cj = col[beg + j]; wj = wnorm[beg + j]; }
        int lim = deg - j0; if (lim > 64) lim = 64;
        for (int jj = 0; jj < lim; jj += 8) {
            int sidx[8]; float sw[8];
            #pragma unroll
            for (int q = 0; q < 8; ++q) {
                sidx[q] = __shfl(cj, jj + q);
                sw[q]   = __shfl(wj, jj + q);
            }
            float4 v0[8], v1[8];
            #pragma unroll
            for (int q = 0; q < 8; ++q) {
                const float* r = pre + (size_t)sidx[q] * DIM;
                v0[q] = *reinterpret_cast<const float4*>(r + c0);
                v1[q] = *reinterpret_cast<const float4*>(r + c1);
            }
            #pragma unroll
            for (int q = 0; q < 8; q += 2) {
                FMA4(s0, sw[q], v0[q]);     FMA4(s1, sw[q], v1[q]);
                FMA4(t0, sw[q+1], v0[q+1]); FMA4(t1, sw[q+1], v1[q+1]);
            }
        }
    }
    s0.x += t0.x; s0.y += t0.y; s0.z += t0.z; s0.w += t0.w;
    s1.x += t1.x; s1.y += t1.y; s1.z += t1.z; s1.w += t1.w;

    if (BIASRELU) {
        s0.x = fmaxf(s0.x, 0.f); s0.y = fmaxf(s0.y, 0.f);
        s0.z = fmaxf(s0.z, 0.f); s0.w = fmaxf(s0.w, 0.f);
        s1.x = fmaxf(s1.x, 0.f); s1.y = fmaxf(s1.y, 0.f);
        s1.z = fmaxf(s1.z, 0.f); s1.w = fmaxf(s1.w, 0.f);
    }
    float* orow = outf + (size_t)node * DIM;
    *reinterpret_cast<float4*>(orow + c0) = s0;
    *reinterpret_cast<float4*>(orow + c1) = s1;
}

// ---------------- pool: SP[0:1000] = A2 rsu rows; SP[1000:2000] = seg-mean of A2 veh ----
__global__ __launch_bounds__(128) void k_pool_sp(const float* __restrict__ A2,
                                                 const int* __restrict__ seg,
                                                 float* __restrict__ SP,
                                                 float* __restrict__ bscale) {
    int s = blockIdx.x;            // 0..999
    int c = threadIdx.x * 4;       // 0..508
    float4 r = *reinterpret_cast<const float4*>(A2 + (size_t)s * DIM + c);
    *reinterpret_cast<float4*>(SP + (size_t)s * DIM + c) = r;

    int beg = seg[s], end = seg[s + 1];
    float4 acc = make_float4(0.f, 0.f, 0.f, 0.f);
    for (int v = beg; v < end; ++v) {
        float4 t = *reinterpret_cast<const float4*>(A2 + (size_t)(NRSU + v) * DIM + c);
        acc.x += t.x; acc.y += t.y; acc.z += t.z; acc.w += t.w;
    }
    float inv = 1.0f / fmaxf((float)(end - beg), 1.0f);
    acc.x *= inv; acc.y *= inv; acc.z *= inv; acc.w *= inv;
    *reinterpret_cast<float4*>(SP + (size_t)(NRSU + s) * DIM + c) = acc;

    if (threadIdx.x == 0) {
        bscale[s] = 1.0f;
        bscale[NRSU + s] = (end > beg) ? 1.0f : 0.0f;   // empty segment: no bias (ref gives 0)
    }
}

extern "C" void kernel_launch(void* const* d_in, const int* in_sizes, int n_in,
                              void* d_out, int out_size, void* d_ws, size_t ws_size,
                              hipStream_t stream) {
    const float* x     = (const float*)d_in[0];
    const int*   ei    = (const int*)d_in[1];
    const int*   batch = (const int*)d_in[2];
    const float* W1    = (const float*)d_in[3];
    const float* b1    = (const float*)d_in[4];
    const float* W2    = (const float*)d_in[5];
    const float* b2    = (const float*)d_in[6];
    float* out = (float*)d_out;

    char* ws = (char*)d_ws;
    const size_t HALF = (size_t)N_NODES * DIM * 2;        // one bf16 plane (51.2 MB)
    // Region R0 (102.4 MB): x split planes; later h1 (fp32); later SP/SPh/SPl/bscale
    unsigned short* Ah = (unsigned short*)(ws);
    unsigned short* Al = (unsigned short*)(ws + HALF);
    float* h1          = (float*)(ws);
    float* SP          = (float*)(ws);                      // 2000x512 fp32 (4.1 MB)
    unsigned short* SPh = (unsigned short*)(ws + (4u << 20));
    unsigned short* SPl = (unsigned short*)(ws + (6u << 20));
    float* bscale      = (float*)(ws + (8u << 20));
    // Region R1 (102.4 MB): GEMM1 out C, then A2 (aggregated h1)
    float* C  = (float*)(ws + 2 * HALF);
    float* A2 = (float*)(ws + 2 * HALF);
    // Small buffers
    char* p = ws + 4 * HALF;
    float* dinv   = (float*)p;                 p += (size_t)N_NODES * 4;
    int*   cnt    = (int*)p;                   p += (size_t)N_NODES * 4;   // reused as fill
    int*   rowptr = (int*)p;                   p += (size_t)(N_NODES + 4) * 4;
    int*   col    = (int*)p;                   p += (size_t)E_EDGES * 4;
    float* wnorm  = (float*)p;                 p += (size_t)E_EDGES * 4;
    int*   bsum   = (int*)p;                   p += 1024;
    int*   seg    = (int*)p;                   p += (size_t)(NRSU + 4) * 4;
    unsigned short* W1h = (unsigned short*)p;  p += (size_t)DIM * DIM * 2;
    unsigned short* W1l = (unsigned short*)p;  p += (size_t)DIM * DIM * 2;
    unsigned short* W2h = (unsigned short*)p;  p += (size_t)DIM * DIM * 2;
    unsigned short* W2l = (unsigned short*)p;  p += (size_t)DIM * DIM * 2;

    dim3 blk(256);
    const int gN = (N_NODES + 255) / 256;
    const int gE = (E_EDGES + 255) / 256;

    // ---- CSR build + norm + weight prep + x split ----
    k_zero_int <<<gN, blk, 0, stream>>>(cnt, N_NODES);
    k_count    <<<gE, blk, 0, stream>>>(ei + E_EDGES, cnt);
    k_scan1    <<<gN, blk, 0, stream>>>(cnt, rowptr, bsum);
    k_scan2    <<<1,  blk, 0, stream>>>(bsum);
    k_scan3    <<<gN, blk, 0, stream>>>(rowptr, bsum, cnt, dinv);
    k_fill     <<<gE, blk, 0, stream>>>(ei, rowptr, cnt, col, dinv, wnorm);
    k_segbounds<<<((N_NODES - NRSU) + 255) / 256, blk, 0, stream>>>(batch, seg);
    k_wsplit   <<<dim3(DIM, 2), blk, 0, stream>>>(W1, W2, W1h, W1l, W2h, W2l);
    k_split    <<<(int)((size_t)N_NODES * DIM / 4 / 256), blk, 0, stream>>>(x, Ah, Al);

    // ---- layer 1: C = x@W1 (MFMA), h1 = relu(S*C + b1) ----
    const int NWG1 = ((N_NODES + 127) / 128) * 4;   // 1564
    k_gemm_mfma<0><<<NWG1, blk, 0, stream>>>(Ah, Al, W1h, W1l, C, N_NODES, nullptr, nullptr);
    k_gather<true><<<(N_NODES + 3) / 4, blk, 0, stream>>>(rowptr, col, wnorm, dinv, C, b1, h1);

    // ---- layer 2 (algebraic reorder): A2 = S*h1; pool; [A2_rsu; P] @ W2 + b2 -> out ----
    k_gather<false><<<(N_NODES + 3) / 4, blk, 0, stream>>>(rowptr, col, wnorm, dinv, h1, nullptr, A2);
    k_pool_sp<<<NRSU, dim3(128), 0, stream>>>(A2, seg, SP, bscale);
    k_split  <<<(2 * NRSU * DIM / 4) / 256, blk, 0, stream>>>(SP, SPh, SPl);   // 1000 blocks
    const int NWG2 = ((2 * NRSU + 127) / 128) * 4;  // 64
    k_gemm_mfma<1><<<NWG2, blk, 0, stream>>>(SPh, SPl, W2h, W2l, out, 2 * NRSU, b2, bscale);
}